// Round 2
// baseline (295.242 us; speedup 1.0000x reference)
//
#include <hip/hip_runtime.h>
#include <hip/hip_bf16.h>

// MetaAdaptiveFusion: B=32, N=2048, H=256, F=8, NH=8, dh=32, 3 meta steps.
// Inputs: fp32 buffers holding bf16-quantized values -> bf16 casts of INPUTS are
// LOSSLESS (docs/u/Wv/Wo/meta). Computed activations (w, ctx, ho, P) are
// hi/lo-split compensated bf16; residual carries stay fp32. Output fp32.
//
// R9: k4_waccum (75us; MfmaUtil 3%, VALUBusy 6%, 64MiB atomic WRITE_SIZE,
// 1.57M LDS bank conflicts -> latency/atomic-bound) replaced by k4r_gemm:
// grid (2 j-half x 32 b) = 64 blocks x 512 thr; each block accumulates its
// W[64 fh][128 j] slice over ALL 2048 n in REGISTERS (no atomics, no memset).
// Scores recomputed per 64-n chunk with u as loop-invariant register A-frags;
// docs reg-prefetched (issue next chunk's loads during current MFMA phases).
// Fragment layouts follow the verified gfx950 conventions (A: m=lane&15,
// k=(lane>>4)*8+j ; B: n=lane&15 same k ; D: col=lane&15, row=(lane>>4)*4+reg).
//
// Pipeline: k1 (qh, u=qh^T Wk/sqrt(dh) bf16, strategy softmax)
//           k2 (MFMA scores -> per-chunk softmax partials pm/pl)
//           k4r (merge partials; chunked score recompute; P hi/lo; reg-accum W)
//           kt (meta -> bf16 metaT[s][x][r], overlays dead u buffer)
//           k5_mfma (ctx=Wv w+bv; ho=Wo ctx+bo; 3 residual meta steps, all MFMA)
//           k6 (strategy combine)

#define B_ 32
#define N_ 2048
#define H_ 256
#define F_ 8
#define FH_ 64
#define NCH2_ 16   // k2: 16 chunks of 128 docs

typedef unsigned short u16;
typedef __attribute__((ext_vector_type(8))) short bf16x8;   // 8 bf16 (4 VGPRs)
typedef __attribute__((ext_vector_type(4))) float f32x4;
#define MFMA(a, b, c) __builtin_amdgcn_mfma_f32_16x16x32_bf16((a), (b), (c), 0, 0, 0)

__device__ __forceinline__ u16 f2b(float x) {   // fp32 -> bf16 bits, RNE
  unsigned u = __builtin_bit_cast(unsigned, x);
  return (u16)((u + 0x7fffu + ((u >> 16) & 1u)) >> 16);
}
__device__ __forceinline__ float b2f(u16 h) {
  unsigned u = ((unsigned)h) << 16;
  return __builtin_bit_cast(float, u);
}

// ---- ws byte layout (3,687,424 B total, proven safe in R6) ----
static constexpr size_t UB_U     = 0;          // u16 [B][FH][H]    1,048,576
                                               //   (metaT u16[3][256][256]=393,216
                                               //    overlays this after k4r)
static constexpr size_t UB_W     = 1048576;    // f32 [B][FH][H]    2,097,152
static constexpr size_t UB_PM    = 3145728;    // f32 [B*FH][16]      131,072
static constexpr size_t UB_PL    = 3276800;    // f32 [B*FH][16]      131,072
static constexpr size_t UB_STRAT = 3424256;    // f32 [B][F]            1,024
static constexpr size_t UB_HO    = 3425280;    // f32 [F][B][H]       262,144

// =============== K1: qh, u, strategy (coalesced wave-per-row dots) ===============
__global__ __launch_bounds__(256) void k1_prep(
    const float* __restrict__ query, const float* __restrict__ ipw,
    const float* __restrict__ ipb, const float* __restrict__ stw,
    const float* __restrict__ stb, u16* __restrict__ u, float* __restrict__ strat)
{
  const int f = blockIdx.x & 7, b = blockIdx.x >> 3;
  const int tid = threadIdx.x, L = tid & 63, w = tid >> 6;
  __shared__ float qh_s[H_];
  __shared__ float logit_s[F_];

  float4 qv = *(const float4*)&query[b * H_ + L * 4];

  // qh rows: wave w handles rows w*64..w*64+63; lane-parallel dot + butterfly
  for (int rr = 0; rr < 64; ++rr) {
    int r = w * 64 + rr;
    float4 a = *(const float4*)&ipw[((size_t)(f * 768) + r) * H_ + L * 4];
    float d = a.x * qv.x + a.y * qv.y + a.z * qv.z + a.w * qv.w;
    #pragma unroll
    for (int m = 32; m; m >>= 1) d += __shfl_xor(d, m, 64);
    if (L == rr) qh_s[r] = d + ipb[f * 768 + r];
  }
  if (f == 0 && w == 0) {  // strategy logits, 8 rows
    for (int rr = 0; rr < 8; ++rr) {
      float4 a = *(const float4*)&stw[rr * H_ + L * 4];
      float d = a.x * qv.x + a.y * qv.y + a.z * qv.z + a.w * qv.w;
      #pragma unroll
      for (int m = 32; m; m >>= 1) d += __shfl_xor(d, m, 64);
      if (L == rr) logit_s[rr] = d + stb[rr];
    }
  }
  __syncthreads();

  // u[b][f*8+h][tid] = (1/sqrt(32)) * sum_d qh[h*32+d] * Wk[h*32+d][tid]  (coalesced)
  const float scale = 0.17677669529663687f;
  for (int h = 0; h < 8; ++h) {
    float acc = 0.f;
    #pragma unroll 8
    for (int d0 = 0; d0 < 32; ++d0) {
      int r = h * 32 + d0;
      acc += qh_s[r] * ipw[((size_t)(f * 768 + 256) + r) * H_ + tid];
    }
    u[((size_t)(b * 64) + f * 8 + h) * H_ + tid] = f2b(acc * scale);
  }
  if (f == 0 && tid == 0) {
    float mx = logit_s[0];
    #pragma unroll
    for (int i = 1; i < F_; ++i) mx = fmaxf(mx, logit_s[i]);
    float s = 0.f, e[F_];
    #pragma unroll
    for (int i = 0; i < F_; ++i) { e[i] = __expf(logit_s[i] - mx); s += e[i]; }
    #pragma unroll
    for (int i = 0; i < F_; ++i) strat[b * F_ + i] = e[i] / s;
  }
}

// =============== K2: MFMA scores -> chunk softmax partials =======================
// grid (16, 32): chunk c = 128 docs. Wave w: rows w*32..+32 (2 M-tiles) x 64 fh.
__global__ __launch_bounds__(256) void k2_stats(
    const float* __restrict__ docs, const float* __restrict__ cw,
    const u16* __restrict__ u, float* __restrict__ pm, float* __restrict__ pl)
{
  const int c = blockIdx.x, b = blockIdx.y;
  const int n0 = c * 128;
  const int tid = threadIdx.x, L = tid & 63, w = tid >> 6;
  const int khi = L >> 4, col = L & 15;

  __shared__ bf16x8 sd8[128 * 9];   // docs chunk [128 n][72 j] bf16 (rows = 9 x b128)
  __shared__ bf16x8 su8[64 * 9];    // u chunk [64 fh][72 j]
  __shared__ float scw[128];
  __shared__ float swred[4][64];
  __shared__ float sbm[64];
  u16* sdu = (u16*)sd8;

  if (tid < 128) scw[tid] = cw[b * N_ + n0 + tid];

  f32x4 acc[2][4];
  #pragma unroll
  for (int t = 0; t < 2; ++t)
    #pragma unroll
    for (int nt = 0; nt < 4; ++nt) acc[t][nt] = (f32x4){0.f, 0.f, 0.f, 0.f};

  for (int j0 = 0; j0 < 256; j0 += 64) {
    if (j0) __syncthreads();
    #pragma unroll
    for (int p = 0; p < 8; ++p) {   // docs [128 n][64 j] fp32 -> bf16
      int idx = tid + 256 * p;
      int n = idx >> 4, jq = (idx & 15) * 4;
      float4 v = *(const float4*)&docs[((size_t)(b * N_) + n0 + n) * H_ + j0 + jq];
      *(ushort4*)&sdu[n * 72 + jq] = make_ushort4(f2b(v.x), f2b(v.y), f2b(v.z), f2b(v.w));
    }
    #pragma unroll
    for (int p = 0; p < 2; ++p) {   // u [64][64]
      int idx = tid + 256 * p;
      int fh = idx >> 3, sub = idx & 7;
      su8[fh * 9 + sub] = *(const bf16x8*)&u[((size_t)(b * 64) + fh) * H_ + j0 + sub * 8];
    }
    __syncthreads();
    #pragma unroll
    for (int kk = 0; kk < 64; kk += 32) {
      bf16x8 a0 = sd8[(w * 32 + col) * 9 + kk / 8 + khi];
      bf16x8 a1 = sd8[(w * 32 + 16 + col) * 9 + kk / 8 + khi];
      #pragma unroll
      for (int nt = 0; nt < 4; ++nt) {
        bf16x8 bb = su8[(nt * 16 + col) * 9 + kk / 8 + khi];
        acc[0][nt] = MFMA(a0, bb, acc[0][nt]);
        acc[1][nt] = MFMA(a1, bb, acc[1][nt]);
      }
    }
  }
  // s = raw * cw ; chunk max / sum-exp per fh
  float cwv[2][4];
  #pragma unroll
  for (int t = 0; t < 2; ++t)
    #pragma unroll
    for (int r = 0; r < 4; ++r) cwv[t][r] = scw[w * 32 + t * 16 + khi * 4 + r];

  float mx[4];
  #pragma unroll
  for (int nt = 0; nt < 4; ++nt) {
    mx[nt] = -3.4e38f;
    #pragma unroll
    for (int t = 0; t < 2; ++t)
      #pragma unroll
      for (int r = 0; r < 4; ++r) {
        float sv = acc[t][nt][r] * cwv[t][r];
        acc[t][nt][r] = sv;
        mx[nt] = fmaxf(mx[nt], sv);
      }
    mx[nt] = fmaxf(mx[nt], __shfl_xor(mx[nt], 16, 64));
    mx[nt] = fmaxf(mx[nt], __shfl_xor(mx[nt], 32, 64));
  }
  if (L < 16) {
    #pragma unroll
    for (int nt = 0; nt < 4; ++nt) swred[w][nt * 16 + L] = mx[nt];
  }
  __syncthreads();
  if (tid < 64)
    sbm[tid] = fmaxf(fmaxf(swred[0][tid], swred[1][tid]),
                     fmaxf(swred[2][tid], swred[3][tid]));
  __syncthreads();
  float ls[4];
  #pragma unroll
  for (int nt = 0; nt < 4; ++nt) {
    float bm = sbm[nt * 16 + col];
    ls[nt] = 0.f;
    #pragma unroll
    for (int t = 0; t < 2; ++t)
      #pragma unroll
      for (int r = 0; r < 4; ++r) ls[nt] += __expf(acc[t][nt][r] - bm);
    ls[nt] += __shfl_xor(ls[nt], 16, 64);
    ls[nt] += __shfl_xor(ls[nt], 32, 64);
  }
  __syncthreads();
  if (L < 16) {
    #pragma unroll
    for (int nt = 0; nt < 4; ++nt) swred[w][nt * 16 + L] = ls[nt];
  }
  __syncthreads();
  if (tid < 64) {
    float bl = swred[0][tid] + swred[1][tid] + swred[2][tid] + swred[3][tid];
    size_t ro = (size_t)(b * 64 + tid) * NCH2_ + c;
    pm[ro] = sbm[tid];
    pl[ro] = bl;
  }
}

// =============== K4R: register-accumulated W GEMM (no atomics) ===================
// grid (2 j-half, 32 b), 512 thr (8 waves). Block owns W[64 fh][128 j] for one b,
// loops over 32 chunks of 64 n: recompute scores (u in regs, docs in LDS),
// P=exp(s-m)/l*cw hi/lo into LDS, W += P @ docs accumulated in registers.
// Wave w: score tiles (ft=w&3, nt0=(w>>2)*2..+1); W j-slice jl = jh*128+w*16+col.
// docs reg-prefetch: next chunk's 8xfloat4 issued before current MFMA phases.
__global__ __launch_bounds__(512) void k4r_gemm(
    const float* __restrict__ docs, const float* __restrict__ cw,
    const u16* __restrict__ u, const float* __restrict__ pm,
    const float* __restrict__ pl, float* __restrict__ wbuf)
{
  const int jh = blockIdx.x, b = blockIdx.y;
  const int tid = threadIdx.x, L = tid & 63, w = tid >> 6;
  const int khi = L >> 4, col = L & 15;
  const int ft = w & 3, nt0 = (w >> 2) * 2;
  const int jl = jh * 128 + w * 16 + col;

  __shared__ u16 sdu[64 * 264];     // docs chunk [64 n][264 j] bf16
  __shared__ u16 phu[64 * 72];      // P_hi [64 fh][72 n]
  __shared__ u16 plou[64 * 72];     // P_lo
  __shared__ float sm_l[64], sl_l[64];

  if (tid < 64) {   // global m, 1/l per fh from chunk partials
    int fh = tid;
    size_t ro = (size_t)(b * 64 + fh) * NCH2_;
    float m = pm[ro];
    for (int cc = 1; cc < NCH2_; ++cc) m = fmaxf(m, pm[ro + cc]);
    float l = 0.f;
    for (int cc = 0; cc < NCH2_; ++cc) l += pl[ro + cc] * __expf(pm[ro + cc] - m);
    sm_l[fh] = m;
    sl_l[fh] = 1.f / l;
  }

  // loop-invariant u A-fragments for this wave's fh-tile ft (A: m=col, k=khi*8+j)
  bf16x8 uf[8];
  #pragma unroll
  for (int ks = 0; ks < 8; ++ks)
    uf[ks] = *(const bf16x8*)&u[((size_t)(b * 64) + ft * 16 + col) * H_ + ks * 32 + khi * 8];

  // prefetch + stage chunk 0
  float4 dv[8];
  #pragma unroll
  for (int p = 0; p < 8; ++p) {
    int idx = tid + 512 * p;
    int n = idx >> 6, jq = (idx & 63) * 4;
    dv[p] = *(const float4*)&docs[((size_t)(b * N_) + n) * H_ + jq];
  }
  #pragma unroll
  for (int p = 0; p < 8; ++p) {
    int idx = tid + 512 * p;
    int n = idx >> 6, jq = (idx & 63) * 4;
    *(ushort4*)&sdu[n * 264 + jq] =
        make_ushort4(f2b(dv[p].x), f2b(dv[p].y), f2b(dv[p].z), f2b(dv[p].w));
  }
  __syncthreads();   // staging + sm_l visible

  f32x4 acc[4];
  #pragma unroll
  for (int mt = 0; mt < 4; ++mt) acc[mt] = (f32x4){0.f, 0.f, 0.f, 0.f};

  for (int nc = 0; nc < 32; ++nc) {
    // issue next chunk's global loads (latency hides under score+W MFMA)
    if (nc < 31) {
      #pragma unroll
      for (int p = 0; p < 8; ++p) {
        int idx = tid + 512 * p;
        int n = idx >> 6, jq = (idx & 63) * 4;
        dv[p] = *(const float4*)&docs[((size_t)(b * N_) + (nc + 1) * 64 + n) * H_ + jq];
      }
    }
    // scores: D[fh(ft)][n(nt0,nt0+1)] = u . docs^T, K=256
    f32x4 sc0 = (f32x4){0.f, 0.f, 0.f, 0.f}, sc1 = sc0;
    #pragma unroll
    for (int ks = 0; ks < 8; ++ks) {
      bf16x8 b0 = *(const bf16x8*)&sdu[((nt0    ) * 16 + col) * 264 + ks * 32 + khi * 8];
      bf16x8 b1 = *(const bf16x8*)&sdu[((nt0 + 1) * 16 + col) * 264 + ks * 32 + khi * 8];
      sc0 = MFMA(uf[ks], b0, sc0);
      sc1 = MFMA(uf[ks], b1, sc1);
    }
    // P epilogue: lane holds (fh=ft*16+khi*4+r, n=nt*16+col)
    {
      int ng = nc * 64 + nt0 * 16 + col;
      float cv0 = cw[(size_t)b * N_ + ng];
      float cv1 = cw[(size_t)b * N_ + ng + 16];
      #pragma unroll
      for (int r = 0; r < 4; ++r) {
        int fh = ft * 16 + khi * 4 + r;
        float m = sm_l[fh], li = sl_l[fh];
        float p0 = __expf(sc0[r] * cv0 - m) * li * cv0;
        float p1 = __expf(sc1[r] * cv1 - m) * li * cv1;
        u16 h0 = f2b(p0), h1 = f2b(p1);
        phu [fh * 72 + nt0 * 16 + col]       = h0;
        plou[fh * 72 + nt0 * 16 + col]       = f2b(p0 - b2f(h0));
        phu [fh * 72 + (nt0 + 1) * 16 + col] = h1;
        plou[fh * 72 + (nt0 + 1) * 16 + col] = f2b(p1 - b2f(h1));
      }
    }
    __syncthreads();   // P visible to all waves

    // W[fh][jl] += sum_n P[fh][n] * docs[n][jl]
    #pragma unroll
    for (int kk = 0; kk < 2; ++kk) {
      bf16x8 bb;
      #pragma unroll
      for (int jj = 0; jj < 8; ++jj)
        bb[jj] = (short)sdu[(kk * 32 + khi * 8 + jj) * 264 + jl];
      #pragma unroll
      for (int mt = 0; mt < 4; ++mt) {
        bf16x8 ah = *(const bf16x8*)&phu [(mt * 16 + col) * 72 + kk * 32 + khi * 8];
        bf16x8 al = *(const bf16x8*)&plou[(mt * 16 + col) * 72 + kk * 32 + khi * 8];
        acc[mt] = MFMA(ah, bb, acc[mt]);
        acc[mt] = MFMA(al, bb, acc[mt]);
      }
    }
    __syncthreads();   // W-phase reads of sdu/P done

    // stage next chunk from regs (vmcnt wait lands here, ~fully covered)
    if (nc < 31) {
      #pragma unroll
      for (int p = 0; p < 8; ++p) {
        int idx = tid + 512 * p;
        int n = idx >> 6, jq = (idx & 63) * 4;
        *(ushort4*)&sdu[n * 264 + jq] =
            make_ushort4(f2b(dv[p].x), f2b(dv[p].y), f2b(dv[p].z), f2b(dv[p].w));
      }
      __syncthreads();
    }
  }
  // plain store (full coverage: fh = 4mt x khi x r = 64; j = 2jh x 8w x 16col = 256)
  #pragma unroll
  for (int mt = 0; mt < 4; ++mt)
    #pragma unroll
    for (int r = 0; r < 4; ++r)
      wbuf[((size_t)(b * 64) + mt * 16 + khi * 4 + r) * H_ + jl] = acc[mt][r];
}

// =============== KT: meta -> bf16 metaT[s][x][r] = meta[s][r][x] =================
// meta is bf16-exact input, so single bf16 (no hi/lo) is lossless. Overlays the
// dead u buffer; must launch after k4r (last reader of u).
__global__ __launch_bounds__(256) void kt_meta(
    const float* __restrict__ meta, u16* __restrict__ metaT)
{
  const int s = blockIdx.x, xg = blockIdx.y;   // s<3, xg<8
  const int x0 = xg * 32;
  const int tid = threadIdx.x;
  __shared__ u16 sT[32 * 264];                 // [32 x][264 r] transposed tile
  #pragma unroll
  for (int p = 0; p < 8; ++p) {                // load 256 r x 32 x, coalesced
    int idx = tid + 256 * p;
    int r = idx >> 3, xq = (idx & 7) * 4;
    float4 v = *(const float4*)&meta[((size_t)(s * 256) + r) * 256 + x0 + xq];
    sT[(xq + 0) * 264 + r] = f2b(v.x);
    sT[(xq + 1) * 264 + r] = f2b(v.y);
    sT[(xq + 2) * 264 + r] = f2b(v.z);
    sT[(xq + 3) * 264 + r] = f2b(v.w);
  }
  __syncthreads();
  #pragma unroll
  for (int p = 0; p < 4; ++p) {                // store rows of metaT, 16B chunks
    int idx = tid + 256 * p;
    int x = idx >> 5, rq = (idx & 31) * 8;
    bf16x8 v = *(bf16x8*)&sT[x * 264 + rq];
    *(bf16x8*)&metaT[((size_t)(s * 256) + x0 + x) * 256 + rq] = v;
  }
}

// =============== K5: MFMA chain ctx -> ho0 -> 3 meta steps =======================
// grid 16 = (f 8) x (b-tile 2 of 16 b), 512 threads (8 waves).
// ctx:  wave w owns NH-head h=w: D[d(2x16 tiles)][b(16)] = Wv_h . w_h^T, K=256
//       panel-staged per 32-k chunk; full K per wave -> no cross-wave reduce.
// ho0:  D[b(16)][x-tile] = ctx . Wo^T + bo ; waves own x-tiles (w*32..+32).
// meta: 3x: ho += ho @ meta[s]; A = ho hi/lo from LDS, B = metaT bf16 (exact)
//       straight from global; residual seed = fp32 accumulator in registers.
// LDS 57,856 B static, regions time-multiplexed:
//   [0,40960)      ctx staging: sWvP[256][40] | sWhiP[128][40] | sWloP[128][40]
//   [0,20480)      ho-phase:    sWo[256][40]
//   [20480,37376)  XB hi/lo [16][264]   (first written in ho0 epilogue)
//   [40960,57856)  XA hi/lo [16][264]   (ctx result)
__global__ __launch_bounds__(512) void k5_mfma(
    const float* __restrict__ ipw, const float* __restrict__ ipb,
    const float* __restrict__ opw, const float* __restrict__ opb,
    const u16* __restrict__ metaT, const float* __restrict__ wbuf,
    float* __restrict__ ho)
{
  const int f = blockIdx.x & 7, b0 = (blockIdx.x >> 3) * 16;
  const int tid = threadIdx.x, L = tid & 63, w = tid >> 6;   // w = wave 0..7
  const int khi = L >> 4, col = L & 15;

  __shared__ char smem[57856];
  u16* sWvP  = (u16*)(smem);             // ctx: [256 (h,d)][40]
  u16* sWhiP = (u16*)(smem + 20480);     // ctx: [128 (h,b)][40]
  u16* sWloP = (u16*)(smem + 30720);
  u16* sWo   = (u16*)(smem);             // ho:  [256 r][40]
  u16* XBh   = (u16*)(smem + 20480);     // [16 b][264 c]
  u16* XBl   = (u16*)(smem + 28928);
  u16* XAh   = (u16*)(smem + 40960);
  u16* XAl   = (u16*)(smem + 49408);

  // ---- ctx: per-ks panels of Wv (all h) and w (all h, hi/lo) ----
  f32x4 cacc0 = (f32x4){0.f, 0.f, 0.f, 0.f};
  f32x4 cacc1 = (f32x4){0.f, 0.f, 0.f, 0.f};
  for (int ks = 0; ks < 8; ++ks) {
    #pragma unroll
    for (int p = 0; p < 4; ++p) {        // Wv panel: 256 rows (h*32+d) x 32 c
      int idx = tid + 512 * p;
      int r = idx >> 3, cq = (idx & 7) * 4;
      float4 v = *(const float4*)&ipw[((size_t)(f * 768 + 512) + r) * 256 + ks * 32 + cq];
      *(ushort4*)&sWvP[r * 40 + cq] = make_ushort4(f2b(v.x), f2b(v.y), f2b(v.z), f2b(v.w));
    }
    #pragma unroll
    for (int p = 0; p < 2; ++p) {        // w panel: 128 rows (h*16+b) x 32 j, hi/lo
      int idx = tid + 512 * p;
      int rr = idx >> 3, cq = (idx & 7) * 4;
      int h = rr >> 4, b = rr & 15;
      float4 v = *(const float4*)&wbuf[((size_t)((b0 + b) * 64) + f * 8 + h) * 256 + ks * 32 + cq];
      u16 hx = f2b(v.x), hy = f2b(v.y), hz = f2b(v.z), hw2 = f2b(v.w);
      *(ushort4*)&sWhiP[rr * 40 + cq] = make_ushort4(hx, hy, hz, hw2);
      *(ushort4*)&sWloP[rr * 40 + cq] = make_ushort4(
          f2b(v.x - b2f(hx)), f2b(v.y - b2f(hy)), f2b(v.z - b2f(hz)), f2b(v.w - b2f(hw2)));
    }
    __syncthreads();
    bf16x8 bh = *(bf16x8*)&sWhiP[(w * 16 + col) * 40 + khi * 8];
    bf16x8 bl = *(bf16x8*)&sWloP[(w * 16 + col) * 40 + khi * 8];
    bf16x8 a0 = *(bf16x8*)&sWvP[(w * 32 + col) * 40 + khi * 8];
    bf16x8 a1 = *(bf16x8*)&sWvP[(w * 32 + 16 + col) * 40 + khi * 8];
    cacc0 = MFMA(a0, bh, cacc0); cacc0 = MFMA(a0, bl, cacc0);
    cacc1 = MFMA(a1, bh, cacc1); cacc1 = MFMA(a1, bl, cacc1);
    __syncthreads();
  }
  // ctx + bv -> XA hi/lo. lane owns (d = mt*16+khi*4+r, b = col) for h = w.
  #pragma unroll
  for (int mt = 0; mt < 2; ++mt) {
    f32x4 cv = mt ? cacc1 : cacc0;
    #pragma unroll
    for (int r = 0; r < 4; ++r) {
      int d = mt * 16 + khi * 4 + r;
      float vv = cv[r] + ipb[f * 768 + 512 + w * 32 + d];
      u16 hi = f2b(vv);
      XAh[col * 264 + w * 32 + d] = hi;
      XAl[col * 264 + w * 32 + d] = f2b(vv - b2f(hi));
    }
  }

  // ---- ho0: D[b][x] = ctx . Wo^T + bo ; waves own x-tiles (w*2+q)*16 ----
  f32x4 hr0, hr1;
  {
    float bo0 = opb[f * 256 + (w * 2 + 0) * 16 + col];
    float bo1 = opb[f * 256 + (w * 2 + 1) * 16 + col];
    hr0 = (f32x4){bo0, bo0, bo0, bo0};
    hr1 = (f32x4){bo1, bo1, bo1, bo1};
  }
  for (int ks = 0; ks < 8; ++ks) {
    #pragma unroll
    for (int p = 0; p < 4; ++p) {        // Wo panel: 256 r x 32 c
      int idx = tid + 512 * p;
      int r = idx >> 3, cq = (idx & 7) * 4;
      float4 v = *(const float4*)&opw[((size_t)(f * 256) + r) * 256 + ks * 32 + cq];
      *(ushort4*)&sWo[r * 40 + cq] = make_ushort4(f2b(v.x), f2b(v.y), f2b(v.z), f2b(v.w));
    }
    __syncthreads();
    bf16x8 ah  = *(bf16x8*)&XAh[col * 264 + ks * 32 + khi * 8];
    bf16x8 al  = *(bf16x8*)&XAl[col * 264 + ks * 32 + khi * 8];
    bf16x8 bw0 = *(bf16x8*)&sWo[((w * 2 + 0) * 16 + col) * 40 + khi * 8];
    bf16x8 bw1 = *(bf16x8*)&sWo[((w * 2 + 1) * 16 + col) * 40 + khi * 8];
    hr0 = MFMA(ah, bw0, hr0); hr0 = MFMA(al, bw0, hr0);
    hr1 = MFMA(ah, bw1, hr1); hr1 = MFMA(al, bw1, hr1);
    __syncthreads();
  }

  // spill ho hi/lo to LDS buffer (Oh/Ol); residual fp32 stays in hr0/hr1
  auto spill = [&](u16* Oh, u16* Ol) {
    #pragma unroll
    for (int q = 0; q < 2; ++q) {
      f32x4 hv = q ? hr1 : hr0;
      int x = (w * 2 + q) * 16 + col;
      #pragma unroll
      for (int r = 0; r < 4; ++r) {
        u16 hi = f2b(hv[r]);
        Oh[(khi * 4 + r) * 264 + x] = hi;
        Ol[(khi * 4 + r) * 264 + x] = f2b(hv[r] - b2f(hi));
      }
    }
  };
  // one meta step: hr += (ho_s) @ meta[s], A = ho_s hi/lo, B = metaT (exact bf16)
  auto meta_mm = [&](const u16* Ah_, const u16* Al_, int s) {
    f32x4 n0 = hr0, n1 = hr1;
    #pragma unroll
    for (int ks = 0; ks < 8; ++ks) {
      bf16x8 ah = *(const bf16x8*)&Ah_[col * 264 + ks * 32 + khi * 8];
      bf16x8 al = *(const bf16x8*)&Al_[col * 264 + ks * 32 + khi * 8];
      const u16* mrow = &metaT[((size_t)(s * 256) + (w * 2) * 16 + col) * 256 + ks * 32 + khi * 8];
      bf16x8 m0 = *(const bf16x8*)mrow;
      bf16x8 m1 = *(const bf16x8*)(mrow + 16 * 256);
      n0 = MFMA(ah, m0, n0); n0 = MFMA(al, m0, n0);
      n1 = MFMA(ah, m1, n1); n1 = MFMA(al, m1, n1);
    }
    hr0 = n0; hr1 = n1;
  };

  spill(XBh, XBl);            // ho0
  __syncthreads();
  meta_mm(XBh, XBl, 0);
  spill(XAh, XAl);
  __syncthreads();
  meta_mm(XAh, XAl, 1);
  spill(XBh, XBl);
  __syncthreads();
  meta_mm(XBh, XBl, 2);

  // final ho (fp32 residual accumulator) -> global [F][B][H]
  #pragma unroll
  for (int q = 0; q < 2; ++q) {
    f32x4 hv = q ? hr1 : hr0;
    int x = (w * 2 + q) * 16 + col;
    #pragma unroll
    for (int r = 0; r < 4; ++r) {
      int b = khi * 4 + r;
      ho[((size_t)(f * B_) + b0 + b) * 256 + x] = hv[r];
    }
  }
}

// =============== K6: strategy combine -> fp32 out ================================
__global__ __launch_bounds__(256) void k6_combine(
    const float* __restrict__ ho, const float* __restrict__ strat,
    float* __restrict__ out)
{
  const int b = blockIdx.x;
  const int tid = threadIdx.x;
  float acc = 0.f;
  #pragma unroll
  for (int f = 0; f < F_; ++f)
    acc += strat[b * F_ + f] * ho[((size_t)(f * B_) + b) * H_ + tid];
  out[b * H_ + tid] = acc;
}

extern "C" void kernel_launch(void* const* d_in, const int* in_sizes, int n_in,
                              void* d_out, int out_size, void* d_ws, size_t ws_size,
                              hipStream_t stream) {
  const float* query = (const float*)d_in[0];
  const float* docs  = (const float*)d_in[1];
  const float* cw    = (const float*)d_in[2];
  // d_in[3] context_history: unused by the reference
  const float* ipw   = (const float*)d_in[4];
  const float* ipb   = (const float*)d_in[5];
  const float* opw   = (const float*)d_in[6];
  const float* opb   = (const float*)d_in[7];
  const float* stw   = (const float*)d_in[8];
  const float* stb   = (const float*)d_in[9];
  const float* meta  = (const float*)d_in[10];
  float* out = (float*)d_out;

  char* base = (char*)d_ws;
  u16*   u     = (u16*)(base + UB_U);
  u16*   metaT = (u16*)(base + UB_U);   // overlays u; written only after k4r
  float* wbuf  = (float*)(base + UB_W);
  float* pm    = (float*)(base + UB_PM);
  float* pl    = (float*)(base + UB_PL);
  float* strat = (float*)(base + UB_STRAT);
  float* ho    = (float*)(base + UB_HO);

  k1_prep<<<dim3(F_ * B_), 256, 0, stream>>>(query, ipw, ipb, stw, stb, u, strat);
  k2_stats<<<dim3(NCH2_, B_), 256, 0, stream>>>(docs, cw, u, pm, pl);
  k4r_gemm<<<dim3(2, B_), 512, 0, stream>>>(docs, cw, u, pm, pl, wbuf);
  kt_meta<<<dim3(3, 8), 256, 0, stream>>>(meta, metaT);
  k5_mfma<<<dim3(16), 512, 0, stream>>>(ipw, ipb, opw, opb, metaT, wbuf, ho);
  k6_combine<<<dim3(B_), 256, 0, stream>>>(ho, strat, out);
}

// Round 3
// 228.163 us; speedup vs baseline: 1.2940x; 1.2940x over previous
//
#include <hip/hip_runtime.h>
#include <hip/hip_bf16.h>

// MetaAdaptiveFusion: B=32, N=2048, H=256, F=8, NH=8, dh=32, 3 meta steps.
// Inputs: fp32 buffers holding bf16-quantized values -> bf16 casts of INPUTS are
// LOSSLESS (docs/u/Wv/Wo/meta). Computed activations (w, ctx, ho, P) are
// hi/lo-split compensated bf16; residual carries stay fp32. Output fp32.
//
// R10: R9's k4r (81us, 64 blocks -> occupancy 5.4%, latency-starved) re-split
// over n: both docs kernels now run 256 blocks (8 n-splits x 32 b) x 512 thr.
//   k2n: chunk=256 n stats (NCH=8), same per-wave tiling as old k2, 8 waves.
//   k4_part: block owns 256-n range, W[64][256] accumulated in registers over
//   4 chunks of 64 n, then ONE atomicAdd per element (4.2M adds, 17MB - low
//   contention, 256 adds/addr). sdu column XOR-swizzle ((n>>3)&3)<<4 spreads
//   the W-phase per-instruction column reads over all 32 banks (was 8-way).
// Fragment layouts follow the verified gfx950 conventions (A: m=lane&15,
// k=(lane>>4)*8+j ; B: n=lane&15 same k ; D: col=lane&15, row=(lane>>4)*4+reg).
//
// Pipeline: memset(w); k1 (qh, u=qh^T Wk/sqrt(dh) bf16, strategy softmax)
//           k2n (MFMA scores -> per-256-chunk softmax partials pm/pl)
//           k4_part (merge partials; score recompute; P hi/lo; reg-W; atomics)
//           kt (meta -> bf16 metaT[s][x][r], overlays dead u buffer)
//           k5_mfma (ctx=Wv w+bv; ho=Wo ctx+bo; 3 residual meta steps, all MFMA)
//           k6 (strategy combine)

#define B_ 32
#define N_ 2048
#define H_ 256
#define F_ 8
#define FH_ 64
#define NCH_ 8   // 8 chunks of 256 docs

typedef unsigned short u16;
typedef __attribute__((ext_vector_type(8))) short bf16x8;   // 8 bf16 (4 VGPRs)
typedef __attribute__((ext_vector_type(4))) float f32x4;
#define MFMA(a, b, c) __builtin_amdgcn_mfma_f32_16x16x32_bf16((a), (b), (c), 0, 0, 0)

__device__ __forceinline__ u16 f2b(float x) {   // fp32 -> bf16 bits, RNE
  unsigned u = __builtin_bit_cast(unsigned, x);
  return (u16)((u + 0x7fffu + ((u >> 16) & 1u)) >> 16);
}
__device__ __forceinline__ float b2f(u16 h) {
  unsigned u = ((unsigned)h) << 16;
  return __builtin_bit_cast(float, u);
}

// ---- ws byte layout (3,687,424 B total, proven safe in R6) ----
static constexpr size_t UB_U     = 0;          // u16 [B][FH][H]    1,048,576
                                               //   (metaT u16[3][256][256]=393,216
                                               //    overlays this after k4_part)
static constexpr size_t UB_W     = 1048576;    // f32 [B][FH][H]    2,097,152
static constexpr size_t UB_PM    = 3145728;    // f32 [B*FH][8]        65,536
static constexpr size_t UB_PL    = 3276800;    // f32 [B*FH][8]        65,536
static constexpr size_t UB_STRAT = 3424256;    // f32 [B][F]            1,024
static constexpr size_t UB_HO    = 3425280;    // f32 [F][B][H]       262,144

// =============== K1: qh, u, strategy (coalesced wave-per-row dots) ===============
__global__ __launch_bounds__(256) void k1_prep(
    const float* __restrict__ query, const float* __restrict__ ipw,
    const float* __restrict__ ipb, const float* __restrict__ stw,
    const float* __restrict__ stb, u16* __restrict__ u, float* __restrict__ strat)
{
  const int f = blockIdx.x & 7, b = blockIdx.x >> 3;
  const int tid = threadIdx.x, L = tid & 63, w = tid >> 6;
  __shared__ float qh_s[H_];
  __shared__ float logit_s[F_];

  float4 qv = *(const float4*)&query[b * H_ + L * 4];

  // qh rows: wave w handles rows w*64..w*64+63; lane-parallel dot + butterfly
  for (int rr = 0; rr < 64; ++rr) {
    int r = w * 64 + rr;
    float4 a = *(const float4*)&ipw[((size_t)(f * 768) + r) * H_ + L * 4];
    float d = a.x * qv.x + a.y * qv.y + a.z * qv.z + a.w * qv.w;
    #pragma unroll
    for (int m = 32; m; m >>= 1) d += __shfl_xor(d, m, 64);
    if (L == rr) qh_s[r] = d + ipb[f * 768 + r];
  }
  if (f == 0 && w == 0) {  // strategy logits, 8 rows
    for (int rr = 0; rr < 8; ++rr) {
      float4 a = *(const float4*)&stw[rr * H_ + L * 4];
      float d = a.x * qv.x + a.y * qv.y + a.z * qv.z + a.w * qv.w;
      #pragma unroll
      for (int m = 32; m; m >>= 1) d += __shfl_xor(d, m, 64);
      if (L == rr) logit_s[rr] = d + stb[rr];
    }
  }
  __syncthreads();

  // u[b][f*8+h][tid] = (1/sqrt(32)) * sum_d qh[h*32+d] * Wk[h*32+d][tid]  (coalesced)
  const float scale = 0.17677669529663687f;
  for (int h = 0; h < 8; ++h) {
    float acc = 0.f;
    #pragma unroll 8
    for (int d0 = 0; d0 < 32; ++d0) {
      int r = h * 32 + d0;
      acc += qh_s[r] * ipw[((size_t)(f * 768 + 256) + r) * H_ + tid];
    }
    u[((size_t)(b * 64) + f * 8 + h) * H_ + tid] = f2b(acc * scale);
  }
  if (f == 0 && tid == 0) {
    float mx = logit_s[0];
    #pragma unroll
    for (int i = 1; i < F_; ++i) mx = fmaxf(mx, logit_s[i]);
    float s = 0.f, e[F_];
    #pragma unroll
    for (int i = 0; i < F_; ++i) { e[i] = __expf(logit_s[i] - mx); s += e[i]; }
    #pragma unroll
    for (int i = 0; i < F_; ++i) strat[b * F_ + i] = e[i] / s;
  }
}

// =============== K2N: MFMA scores -> 256-chunk softmax partials ==================
// grid (8, 32): chunk = 256 docs. 512 thr, 8 waves. Wave w: n-rows w*32..+32
// (2 M-tiles) x 64 fh. Reg-prefetched staging, same fragment math as old k2.
__global__ __launch_bounds__(512) void k2_stats(
    const float* __restrict__ docs, const float* __restrict__ cw,
    const u16* __restrict__ u, float* __restrict__ pm, float* __restrict__ pl)
{
  const int ns = blockIdx.x, b = blockIdx.y;
  const int n0 = ns * 256;
  const int tid = threadIdx.x, L = tid & 63, w = tid >> 6;
  const int khi = L >> 4, col = L & 15;

  __shared__ u16 sdu[256 * 72];     // docs [256 n][72 j] bf16 (j0-window of 64)
  __shared__ bf16x8 su8[64 * 9];    // u chunk [64 fh][72 j]
  __shared__ float scw[256];
  __shared__ float swred[8][64];
  __shared__ float sbm[64];

  if (tid < 256) scw[tid] = cw[b * N_ + n0 + tid];

  f32x4 acc[2][4];
  #pragma unroll
  for (int t = 0; t < 2; ++t)
    #pragma unroll
    for (int nt = 0; nt < 4; ++nt) acc[t][nt] = (f32x4){0.f, 0.f, 0.f, 0.f};

  // prefetch j0=0 docs window
  float4 dv[8];
  #pragma unroll
  for (int p = 0; p < 8; ++p) {
    int idx = tid + 512 * p;
    int n = idx >> 4, jq = (idx & 15) * 4;
    dv[p] = *(const float4*)&docs[((size_t)(b * N_) + n0 + n) * H_ + jq];
  }

  for (int jv = 0; jv < 4; ++jv) {
    const int j0 = jv * 64;
    if (jv) __syncthreads();     // previous window fully consumed
    {  // u [64][64-slice]: one bf16x8 per thread
      int fh = tid >> 3, sub = tid & 7;
      su8[fh * 9 + sub] = *(const bf16x8*)&u[((size_t)(b * 64) + fh) * H_ + j0 + sub * 8];
    }
    #pragma unroll
    for (int p = 0; p < 8; ++p) {   // stage docs window from regs
      int idx = tid + 512 * p;
      int n = idx >> 4, jq = (idx & 15) * 4;
      *(ushort4*)&sdu[n * 72 + jq] =
          make_ushort4(f2b(dv[p].x), f2b(dv[p].y), f2b(dv[p].z), f2b(dv[p].w));
    }
    if (jv < 3) {                   // prefetch next window (hides under MFMA)
      #pragma unroll
      for (int p = 0; p < 8; ++p) {
        int idx = tid + 512 * p;
        int n = idx >> 4, jq = (idx & 15) * 4;
        dv[p] = *(const float4*)&docs[((size_t)(b * N_) + n0 + n) * H_ + j0 + 64 + jq];
      }
    }
    __syncthreads();
    #pragma unroll
    for (int kk = 0; kk < 64; kk += 32) {
      bf16x8 a0 = *(const bf16x8*)&sdu[(w * 32 + col) * 72 + kk + khi * 8];
      bf16x8 a1 = *(const bf16x8*)&sdu[(w * 32 + 16 + col) * 72 + kk + khi * 8];
      #pragma unroll
      for (int nt = 0; nt < 4; ++nt) {
        bf16x8 bb = su8[(nt * 16 + col) * 9 + kk / 8 + khi];
        acc[0][nt] = MFMA(a0, bb, acc[0][nt]);
        acc[1][nt] = MFMA(a1, bb, acc[1][nt]);
      }
    }
  }
  // s = raw * cw ; chunk max / sum-exp per fh
  float cwv[2][4];
  #pragma unroll
  for (int t = 0; t < 2; ++t)
    #pragma unroll
    for (int r = 0; r < 4; ++r) cwv[t][r] = scw[w * 32 + t * 16 + khi * 4 + r];

  float mx[4];
  #pragma unroll
  for (int nt = 0; nt < 4; ++nt) {
    mx[nt] = -3.4e38f;
    #pragma unroll
    for (int t = 0; t < 2; ++t)
      #pragma unroll
      for (int r = 0; r < 4; ++r) {
        float sv = acc[t][nt][r] * cwv[t][r];
        acc[t][nt][r] = sv;
        mx[nt] = fmaxf(mx[nt], sv);
      }
    mx[nt] = fmaxf(mx[nt], __shfl_xor(mx[nt], 16, 64));
    mx[nt] = fmaxf(mx[nt], __shfl_xor(mx[nt], 32, 64));
  }
  if (L < 16) {
    #pragma unroll
    for (int nt = 0; nt < 4; ++nt) swred[w][nt * 16 + L] = mx[nt];
  }
  __syncthreads();
  if (tid < 64) {
    float m = swred[0][tid];
    #pragma unroll
    for (int ww = 1; ww < 8; ++ww) m = fmaxf(m, swred[ww][tid]);
    sbm[tid] = m;
  }
  __syncthreads();
  float ls[4];
  #pragma unroll
  for (int nt = 0; nt < 4; ++nt) {
    float bm = sbm[nt * 16 + col];
    ls[nt] = 0.f;
    #pragma unroll
    for (int t = 0; t < 2; ++t)
      #pragma unroll
      for (int r = 0; r < 4; ++r) ls[nt] += __expf(acc[t][nt][r] - bm);
    ls[nt] += __shfl_xor(ls[nt], 16, 64);
    ls[nt] += __shfl_xor(ls[nt], 32, 64);
  }
  __syncthreads();
  if (L < 16) {
    #pragma unroll
    for (int nt = 0; nt < 4; ++nt) swred[w][nt * 16 + L] = ls[nt];
  }
  __syncthreads();
  if (tid < 64) {
    float bl = 0.f;
    #pragma unroll
    for (int ww = 0; ww < 8; ++ww) bl += swred[ww][tid];
    size_t ro = (size_t)(b * 64 + tid) * NCH_ + ns;
    pm[ro] = sbm[tid];
    pl[ro] = bl;
  }
}

// =============== K4_PART: n-split register-W GEMM + atomic merge =================
// grid (8 ns, 32 b), 512 thr (8 waves). Block: n-range ns*256..+256, all 64 fh,
// all 256 j, W in registers (acc2[4][2] f32x4 / thread), 4 chunks of 64 n.
// Scores: wave w -> (ft=w&3 fh-tile, nt0=(w>>2)*2 n-tiles), u in regs.
// W: wave w -> j-slice w*32..+32 (2 j-tiles) x 4 fh-tiles.
// sdu column XOR-swizzle ((n>>3)&3)<<4: W-phase column reads conflict-free.
__global__ __launch_bounds__(512) void k4_part(
    const float* __restrict__ docs, const float* __restrict__ cw,
    const u16* __restrict__ u, const float* __restrict__ pm,
    const float* __restrict__ pl, float* __restrict__ wbuf)
{
  const int ns = blockIdx.x, b = blockIdx.y;
  const int n0 = ns * 256;
  const int tid = threadIdx.x, L = tid & 63, w = tid >> 6;
  const int khi = L >> 4, col = L & 15;
  const int ft = w & 3, nt0 = (w >> 2) * 2;

  __shared__ u16 sdu[64 * 264];     // docs chunk [64 n][264 j] bf16, col-swizzled
  __shared__ u16 phu[64 * 72];      // P_hi [64 fh][72 n]
  __shared__ u16 plou[64 * 72];     // P_lo
  __shared__ float sm_l[64], sl_l[64];

  if (tid < 64) {   // global m, 1/l per fh from chunk partials
    size_t ro = (size_t)(b * 64 + tid) * NCH_;
    float m = pm[ro];
    for (int cc = 1; cc < NCH_; ++cc) m = fmaxf(m, pm[ro + cc]);
    float l = 0.f;
    for (int cc = 0; cc < NCH_; ++cc) l += pl[ro + cc] * __expf(pm[ro + cc] - m);
    sm_l[tid] = m;
    sl_l[tid] = 1.f / l;
  }

  // loop-invariant u A-fragments for this wave's fh-tile ft
  bf16x8 uf[8];
  #pragma unroll
  for (int ks = 0; ks < 8; ++ks)
    uf[ks] = *(const bf16x8*)&u[((size_t)(b * 64) + ft * 16 + col) * H_ + ks * 32 + khi * 8];

  // prefetch + stage chunk 0 (swizzled store)
  float4 dv[8];
  #pragma unroll
  for (int p = 0; p < 8; ++p) {
    int idx = tid + 512 * p;
    int n = idx >> 6, jq = (idx & 63) * 4;
    dv[p] = *(const float4*)&docs[((size_t)(b * N_) + n0 + n) * H_ + jq];
  }
  #pragma unroll
  for (int p = 0; p < 8; ++p) {
    int idx = tid + 512 * p;
    int n = idx >> 6, jq = (idx & 63) * 4;
    *(ushort4*)&sdu[n * 264 + (jq ^ (((n >> 3) & 3) << 4))] =
        make_ushort4(f2b(dv[p].x), f2b(dv[p].y), f2b(dv[p].z), f2b(dv[p].w));
  }
  __syncthreads();   // staging + sm_l visible

  f32x4 acc2[4][2];
  #pragma unroll
  for (int mt = 0; mt < 4; ++mt)
    #pragma unroll
    for (int jt = 0; jt < 2; ++jt) acc2[mt][jt] = (f32x4){0.f, 0.f, 0.f, 0.f};

  for (int nc = 0; nc < 4; ++nc) {
    // issue next chunk's global loads (latency hides under MFMA phases)
    if (nc < 3) {
      #pragma unroll
      for (int p = 0; p < 8; ++p) {
        int idx = tid + 512 * p;
        int n = idx >> 6, jq = (idx & 63) * 4;
        dv[p] = *(const float4*)&docs[((size_t)(b * N_) + n0 + (nc + 1) * 64 + n) * H_ + jq];
      }
    }
    // scores: D[fh(ft)][n(nt0,nt0+1)] = u . docs^T, K=256
    f32x4 sc0 = (f32x4){0.f, 0.f, 0.f, 0.f}, sc1 = sc0;
    const int nr0 = nt0 * 16 + col, nr1 = (nt0 + 1) * 16 + col;
    const int sw0 = ((nr0 >> 3) & 3) << 4, sw1 = ((nr1 >> 3) & 3) << 4;
    #pragma unroll
    for (int ks = 0; ks < 8; ++ks) {
      bf16x8 b0 = *(const bf16x8*)&sdu[nr0 * 264 + ((ks * 32 + khi * 8) ^ sw0)];
      bf16x8 b1 = *(const bf16x8*)&sdu[nr1 * 264 + ((ks * 32 + khi * 8) ^ sw1)];
      sc0 = MFMA(uf[ks], b0, sc0);
      sc1 = MFMA(uf[ks], b1, sc1);
    }
    // P epilogue: lane holds (fh=ft*16+khi*4+r, n=nt*16+col)
    {
      int ng = n0 + nc * 64 + nt0 * 16 + col;
      float cv0 = cw[(size_t)b * N_ + ng];
      float cv1 = cw[(size_t)b * N_ + ng + 16];
      #pragma unroll
      for (int r = 0; r < 4; ++r) {
        int fh = ft * 16 + khi * 4 + r;
        float m = sm_l[fh], li = sl_l[fh];
        float p0 = __expf(sc0[r] * cv0 - m) * li * cv0;
        float p1 = __expf(sc1[r] * cv1 - m) * li * cv1;
        u16 h0 = f2b(p0), h1 = f2b(p1);
        phu [fh * 72 + nt0 * 16 + col]       = h0;
        plou[fh * 72 + nt0 * 16 + col]       = f2b(p0 - b2f(h0));
        phu [fh * 72 + (nt0 + 1) * 16 + col] = h1;
        plou[fh * 72 + (nt0 + 1) * 16 + col] = f2b(p1 - b2f(h1));
      }
    }
    __syncthreads();   // P visible to all waves; sdu intact

    // W[fh][j] += sum_n P[fh][n] * docs[n][j]; wave owns j = w*32 + jt*16 + col
    #pragma unroll
    for (int kk = 0; kk < 2; ++kk) {
      #pragma unroll
      for (int jt = 0; jt < 2; ++jt) {
        int j = w * 32 + jt * 16 + col;
        bf16x8 bb;
        #pragma unroll
        for (int jj = 0; jj < 8; ++jj)
          bb[jj] = (short)sdu[(kk * 32 + khi * 8 + jj) * 264 + (j ^ (khi << 4))];
        #pragma unroll
        for (int mt = 0; mt < 4; ++mt) {
          bf16x8 ah = *(const bf16x8*)&phu [(mt * 16 + col) * 72 + kk * 32 + khi * 8];
          bf16x8 al = *(const bf16x8*)&plou[(mt * 16 + col) * 72 + kk * 32 + khi * 8];
          acc2[mt][jt] = MFMA(ah, bb, acc2[mt][jt]);
          acc2[mt][jt] = MFMA(al, bb, acc2[mt][jt]);
        }
      }
    }
    __syncthreads();   // all reads of sdu/P done

    if (nc < 3) {      // stage next chunk from regs
      #pragma unroll
      for (int p = 0; p < 8; ++p) {
        int idx = tid + 512 * p;
        int n = idx >> 6, jq = (idx & 63) * 4;
        *(ushort4*)&sdu[n * 264 + (jq ^ (((n >> 3) & 3) << 4))] =
            make_ushort4(f2b(dv[p].x), f2b(dv[p].y), f2b(dv[p].z), f2b(dv[p].w));
      }
      __syncthreads();
    }
  }
  // merge partial W (one atomic per element; 8 adds per address across ns)
  #pragma unroll
  for (int mt = 0; mt < 4; ++mt)
    #pragma unroll
    for (int jt = 0; jt < 2; ++jt)
      #pragma unroll
      for (int r = 0; r < 4; ++r) {
        int fh = mt * 16 + khi * 4 + r;
        int j = w * 32 + jt * 16 + col;
        atomicAdd(&wbuf[((size_t)(b * 64) + fh) * H_ + j], acc2[mt][jt][r]);
      }
}

// =============== KT: meta -> bf16 metaT[s][x][r] = meta[s][r][x] =================
// meta is bf16-exact input, so single bf16 (no hi/lo) is lossless. Overlays the
// dead u buffer; must launch after k4_part (last reader of u).
__global__ __launch_bounds__(256) void kt_meta(
    const float* __restrict__ meta, u16* __restrict__ metaT)
{
  const int s = blockIdx.x, xg = blockIdx.y;   // s<3, xg<8
  const int x0 = xg * 32;
  const int tid = threadIdx.x;
  __shared__ u16 sT[32 * 264];                 // [32 x][264 r] transposed tile
  #pragma unroll
  for (int p = 0; p < 8; ++p) {                // load 256 r x 32 x, coalesced
    int idx = tid + 256 * p;
    int r = idx >> 3, xq = (idx & 7) * 4;
    float4 v = *(const float4*)&meta[((size_t)(s * 256) + r) * 256 + x0 + xq];
    sT[(xq + 0) * 264 + r] = f2b(v.x);
    sT[(xq + 1) * 264 + r] = f2b(v.y);
    sT[(xq + 2) * 264 + r] = f2b(v.z);
    sT[(xq + 3) * 264 + r] = f2b(v.w);
  }
  __syncthreads();
  #pragma unroll
  for (int p = 0; p < 4; ++p) {                // store rows of metaT, 16B chunks
    int idx = tid + 256 * p;
    int x = idx >> 5, rq = (idx & 31) * 8;
    bf16x8 v = *(bf16x8*)&sT[x * 264 + rq];
    *(bf16x8*)&metaT[((size_t)(s * 256) + x0 + x) * 256 + rq] = v;
  }
}

// =============== K5: MFMA chain ctx -> ho0 -> 3 meta steps =======================
// grid 16 = (f 8) x (b-tile 2 of 16 b), 512 threads (8 waves).
__global__ __launch_bounds__(512) void k5_mfma(
    const float* __restrict__ ipw, const float* __restrict__ ipb,
    const float* __restrict__ opw, const float* __restrict__ opb,
    const u16* __restrict__ metaT, const float* __restrict__ wbuf,
    float* __restrict__ ho)
{
  const int f = blockIdx.x & 7, b0 = (blockIdx.x >> 3) * 16;
  const int tid = threadIdx.x, L = tid & 63, w = tid >> 6;   // w = wave 0..7
  const int khi = L >> 4, col = L & 15;

  __shared__ char smem[57856];
  u16* sWvP  = (u16*)(smem);             // ctx: [256 (h,d)][40]
  u16* sWhiP = (u16*)(smem + 20480);     // ctx: [128 (h,b)][40]
  u16* sWloP = (u16*)(smem + 30720);
  u16* sWo   = (u16*)(smem);             // ho:  [256 r][40]
  u16* XBh   = (u16*)(smem + 20480);     // [16 b][264 c]
  u16* XBl   = (u16*)(smem + 28928);
  u16* XAh   = (u16*)(smem + 40960);
  u16* XAl   = (u16*)(smem + 49408);

  // ---- ctx: per-ks panels of Wv (all h) and w (all h, hi/lo) ----
  f32x4 cacc0 = (f32x4){0.f, 0.f, 0.f, 0.f};
  f32x4 cacc1 = (f32x4){0.f, 0.f, 0.f, 0.f};
  for (int ks = 0; ks < 8; ++ks) {
    #pragma unroll
    for (int p = 0; p < 4; ++p) {        // Wv panel: 256 rows (h*32+d) x 32 c
      int idx = tid + 512 * p;
      int r = idx >> 3, cq = (idx & 7) * 4;
      float4 v = *(const float4*)&ipw[((size_t)(f * 768 + 512) + r) * 256 + ks * 32 + cq];
      *(ushort4*)&sWvP[r * 40 + cq] = make_ushort4(f2b(v.x), f2b(v.y), f2b(v.z), f2b(v.w));
    }
    #pragma unroll
    for (int p = 0; p < 2; ++p) {        // w panel: 128 rows (h*16+b) x 32 j, hi/lo
      int idx = tid + 512 * p;
      int rr = idx >> 3, cq = (idx & 7) * 4;
      int h = rr >> 4, b = rr & 15;
      float4 v = *(const float4*)&wbuf[((size_t)((b0 + b) * 64) + f * 8 + h) * 256 + ks * 32 + cq];
      u16 hx = f2b(v.x), hy = f2b(v.y), hz = f2b(v.z), hw2 = f2b(v.w);
      *(ushort4*)&sWhiP[rr * 40 + cq] = make_ushort4(hx, hy, hz, hw2);
      *(ushort4*)&sWloP[rr * 40 + cq] = make_ushort4(
          f2b(v.x - b2f(hx)), f2b(v.y - b2f(hy)), f2b(v.z - b2f(hz)), f2b(v.w - b2f(hw2)));
    }
    __syncthreads();
    bf16x8 bh = *(bf16x8*)&sWhiP[(w * 16 + col) * 40 + khi * 8];
    bf16x8 bl = *(bf16x8*)&sWloP[(w * 16 + col) * 40 + khi * 8];
    bf16x8 a0 = *(bf16x8*)&sWvP[(w * 32 + col) * 40 + khi * 8];
    bf16x8 a1 = *(bf16x8*)&sWvP[(w * 32 + 16 + col) * 40 + khi * 8];
    cacc0 = MFMA(a0, bh, cacc0); cacc0 = MFMA(a0, bl, cacc0);
    cacc1 = MFMA(a1, bh, cacc1); cacc1 = MFMA(a1, bl, cacc1);
    __syncthreads();
  }
  // ctx + bv -> XA hi/lo. lane owns (d = mt*16+khi*4+r, b = col) for h = w.
  #pragma unroll
  for (int mt = 0; mt < 2; ++mt) {
    f32x4 cv = mt ? cacc1 : cacc0;
    #pragma unroll
    for (int r = 0; r < 4; ++r) {
      int d = mt * 16 + khi * 4 + r;
      float vv = cv[r] + ipb[f * 768 + 512 + w * 32 + d];
      u16 hi = f2b(vv);
      XAh[col * 264 + w * 32 + d] = hi;
      XAl[col * 264 + w * 32 + d] = f2b(vv - b2f(hi));
    }
  }

  // ---- ho0: D[b][x] = ctx . Wo^T + bo ; waves own x-tiles (w*2+q)*16 ----
  f32x4 hr0, hr1;
  {
    float bo0 = opb[f * 256 + (w * 2 + 0) * 16 + col];
    float bo1 = opb[f * 256 + (w * 2 + 1) * 16 + col];
    hr0 = (f32x4){bo0, bo0, bo0, bo0};
    hr1 = (f32x4){bo1, bo1, bo1, bo1};
  }
  for (int ks = 0; ks < 8; ++ks) {
    #pragma unroll
    for (int p = 0; p < 4; ++p) {        // Wo panel: 256 r x 32 c
      int idx = tid + 512 * p;
      int r = idx >> 3, cq = (idx & 7) * 4;
      float4 v = *(const float4*)&opw[((size_t)(f * 256) + r) * 256 + ks * 32 + cq];
      *(ushort4*)&sWo[r * 40 + cq] = make_ushort4(f2b(v.x), f2b(v.y), f2b(v.z), f2b(v.w));
    }
    __syncthreads();
    bf16x8 ah  = *(bf16x8*)&XAh[col * 264 + ks * 32 + khi * 8];
    bf16x8 al  = *(bf16x8*)&XAl[col * 264 + ks * 32 + khi * 8];
    bf16x8 bw0 = *(bf16x8*)&sWo[((w * 2 + 0) * 16 + col) * 40 + khi * 8];
    bf16x8 bw1 = *(bf16x8*)&sWo[((w * 2 + 1) * 16 + col) * 40 + khi * 8];
    hr0 = MFMA(ah, bw0, hr0); hr0 = MFMA(al, bw0, hr0);
    hr1 = MFMA(ah, bw1, hr1); hr1 = MFMA(al, bw1, hr1);
    __syncthreads();
  }

  // spill ho hi/lo to LDS buffer (Oh/Ol); residual fp32 stays in hr0/hr1
  auto spill = [&](u16* Oh, u16* Ol) {
    #pragma unroll
    for (int q = 0; q < 2; ++q) {
      f32x4 hv = q ? hr1 : hr0;
      int x = (w * 2 + q) * 16 + col;
      #pragma unroll
      for (int r = 0; r < 4; ++r) {
        u16 hi = f2b(hv[r]);
        Oh[(khi * 4 + r) * 264 + x] = hi;
        Ol[(khi * 4 + r) * 264 + x] = f2b(hv[r] - b2f(hi));
      }
    }
  };
  // one meta step: hr += (ho_s) @ meta[s], A = ho_s hi/lo, B = metaT (exact bf16)
  auto meta_mm = [&](const u16* Ah_, const u16* Al_, int s) {
    f32x4 n0 = hr0, n1 = hr1;
    #pragma unroll
    for (int ks = 0; ks < 8; ++ks) {
      bf16x8 ah = *(const bf16x8*)&Ah_[col * 264 + ks * 32 + khi * 8];
      bf16x8 al = *(const bf16x8*)&Al_[col * 264 + ks * 32 + khi * 8];
      const u16* mrow = &metaT[((size_t)(s * 256) + (w * 2) * 16 + col) * 256 + ks * 32 + khi * 8];
      bf16x8 m0 = *(const bf16x8*)mrow;
      bf16x8 m1 = *(const bf16x8*)(mrow + 16 * 256);
      n0 = MFMA(ah, m0, n0); n0 = MFMA(al, m0, n0);
      n1 = MFMA(ah, m1, n1); n1 = MFMA(al, m1, n1);
    }
    hr0 = n0; hr1 = n1;
  };

  spill(XBh, XBl);            // ho0
  __syncthreads();
  meta_mm(XBh, XBl, 0);
  spill(XAh, XAl);
  __syncthreads();
  meta_mm(XAh, XAl, 1);
  spill(XBh, XBl);
  __syncthreads();
  meta_mm(XBh, XBl, 2);

  // final ho (fp32 residual accumulator) -> global [F][B][H]
  #pragma unroll
  for (int q = 0; q < 2; ++q) {
    f32x4 hv = q ? hr1 : hr0;
    int x = (w * 2 + q) * 16 + col;
    #pragma unroll
    for (int r = 0; r < 4; ++r) {
      int b = khi * 4 + r;
      ho[((size_t)(f * B_) + b0 + b) * 256 + x] = hv[r];
    }
  }
}

// =============== K6: strategy combine -> fp32 out ================================
__global__ __launch_bounds__(256) void k6_combine(
    const float* __restrict__ ho, const float* __restrict__ strat,
    float* __restrict__ out)
{
  const int b = blockIdx.x;
  const int tid = threadIdx.x;
  float acc = 0.f;
  #pragma unroll
  for (int f = 0; f < F_; ++f)
    acc += strat[b * F_ + f] * ho[((size_t)(f * B_) + b) * H_ + tid];
  out[b * H_ + tid] = acc;
}

extern "C" void kernel_launch(void* const* d_in, const int* in_sizes, int n_in,
                              void* d_out, int out_size, void* d_ws, size_t ws_size,
                              hipStream_t stream) {
  const float* query = (const float*)d_in[0];
  const float* docs  = (const float*)d_in[1];
  const float* cw    = (const float*)d_in[2];
  // d_in[3] context_history: unused by the reference
  const float* ipw   = (const float*)d_in[4];
  const float* ipb   = (const float*)d_in[5];
  const float* opw   = (const float*)d_in[6];
  const float* opb   = (const float*)d_in[7];
  const float* stw   = (const float*)d_in[8];
  const float* stb   = (const float*)d_in[9];
  const float* meta  = (const float*)d_in[10];
  float* out = (float*)d_out;

  char* base = (char*)d_ws;
  u16*   u     = (u16*)(base + UB_U);
  u16*   metaT = (u16*)(base + UB_U);   // overlays u; written only after k4_part
  float* wbuf  = (float*)(base + UB_W);
  float* pm    = (float*)(base + UB_PM);
  float* pl    = (float*)(base + UB_PL);
  float* strat = (float*)(base + UB_STRAT);
  float* ho    = (float*)(base + UB_HO);

  hipMemsetAsync(wbuf, 0, (size_t)B_ * FH_ * H_ * sizeof(float), stream);
  k1_prep<<<dim3(F_ * B_), 256, 0, stream>>>(query, ipw, ipb, stw, stb, u, strat);
  k2_stats<<<dim3(NCH_, B_), 512, 0, stream>>>(docs, cw, u, pm, pl);
  k4_part<<<dim3(NCH_, B_), 512, 0, stream>>>(docs, cw, u, pm, pl, wbuf);
  kt_meta<<<dim3(3, 8), 256, 0, stream>>>(meta, metaT);
  k5_mfma<<<dim3(16), 512, 0, stream>>>(ipw, ipb, opw, opb, metaT, wbuf, ho);
  k6_combine<<<dim3(B_), 256, 0, stream>>>(ho, strat, out);
}

// Round 4
// 209.150 us; speedup vs baseline: 1.4116x; 1.0909x over previous
//
#include <hip/hip_runtime.h>
#include <hip/hip_bf16.h>

// MetaAdaptiveFusion: B=32, N=2048, H=256, F=8, NH=8, dh=32, 3 meta steps.
// Inputs: fp32 buffers holding bf16-quantized values -> bf16 casts of INPUTS are
// LOSSLESS (query/docs/u/Wq/Wk/Wv/Wo/stw/meta). Computed activations (qh, w,
// ctx, ho, P) are hi/lo-split compensated bf16; residual carries stay fp32.
//
// R11: k1_prep (51-65us; MfmaUtil 0, VALUBusy 4%, occupancy 10% -> serial
// latency-bound wave-per-row dots) replaced by k1_mfma: grid (8 f x 2 h-half),
// 512 thr. Phase 1: qh = Wq.query^T + bq as MFMA GEMM (panel-staged Wq,
// query as loop-invariant register B-frags), hi/lo split to LDS. Phase 2:
// u_h = Wk_h^T.qh_h^T per head (K=32, 2 MFMA hi/lo per tile); Wk staged
// transposed with d-block XOR swizzle (aligned b128 frags, low conflicts).
// Strategy logits via MFMA on wave 0 of block 0. Fragment layouts follow the
// verified gfx950 conventions (A: m=lane&15, k=(lane>>4)*8+j ; B: n=lane&15
// same k ; D: col=lane&15 (B's n), row=(lane>>4)*4+reg (A's m)).
//
// Pipeline: memset(w); k1_mfma (qh; u; strategy)
//           k2n (MFMA scores -> per-256-chunk softmax partials pm/pl)
//           k4_part (merge partials; score recompute; P hi/lo; reg-W; atomics)
//           kt (meta -> bf16 metaT[s][x][r], overlays dead u buffer)
//           k5_mfma (ctx=Wv w+bv; ho=Wo ctx+bo; 3 residual meta steps, all MFMA)
//           k6 (strategy combine)

#define B_ 32
#define N_ 2048
#define H_ 256
#define F_ 8
#define FH_ 64
#define NCH_ 8   // 8 chunks of 256 docs

typedef unsigned short u16;
typedef __attribute__((ext_vector_type(8))) short bf16x8;   // 8 bf16 (4 VGPRs)
typedef __attribute__((ext_vector_type(4))) float f32x4;
#define MFMA(a, b, c) __builtin_amdgcn_mfma_f32_16x16x32_bf16((a), (b), (c), 0, 0, 0)

__device__ __forceinline__ u16 f2b(float x) {   // fp32 -> bf16 bits, RNE
  unsigned u = __builtin_bit_cast(unsigned, x);
  return (u16)((u + 0x7fffu + ((u >> 16) & 1u)) >> 16);
}
__device__ __forceinline__ float b2f(u16 h) {
  unsigned u = ((unsigned)h) << 16;
  return __builtin_bit_cast(float, u);
}

// ---- ws byte layout (3,687,424 B total, proven safe in R6) ----
static constexpr size_t UB_U     = 0;          // u16 [B][FH][H]    1,048,576
                                               //   (metaT u16[3][256][256]=393,216
                                               //    overlays this after k4_part)
static constexpr size_t UB_W     = 1048576;    // f32 [B][FH][H]    2,097,152
static constexpr size_t UB_PM    = 3145728;    // f32 [B*FH][8]        65,536
static constexpr size_t UB_PL    = 3276800;    // f32 [B*FH][8]        65,536
static constexpr size_t UB_STRAT = 3424256;    // f32 [B][F]            1,024
static constexpr size_t UB_HO    = 3425280;    // f32 [F][B][H]       262,144

// =============== K1: MFMA qh -> u, strategy ======================================
// grid 16 = (f 8) x (h-half 2), 512 thr (8 waves).
// Phase 1: qh[r][b], r-half = hf*128..+128. Wave w owns m-tile r = w*16..+16,
//          n-tiles b 0..31 (bt 0,1). Wq panel [128 r][32 k] staged per ks.
// Phase 2: per hh<4 (h = hf*4+hh): u[j][b] = sum_d Wk[h*32+d][j] qh[b][h*32+d];
//          Wk staged transposed [256 j][32 d] with d-block swizzle; wave w owns
//          j-tiles w*2, w*2+1 x bt 0,1; K=32 -> 1 MFMA per operand half.
__global__ __launch_bounds__(512) void k1_mfma(
    const float* __restrict__ query, const float* __restrict__ ipw,
    const float* __restrict__ ipb, const float* __restrict__ stw,
    const float* __restrict__ stb, u16* __restrict__ u, float* __restrict__ strat)
{
  const int f = blockIdx.x >> 1, hf = blockIdx.x & 1;
  const int tid = threadIdx.x, L = tid & 63, w = tid >> 6;
  const int khi = L >> 4, col = L & 15;

  __shared__ u16 sW[256 * 40];     // phase1: Wq panel [128][40]; phase2: WkT [256 j][40 d-swz]
  __shared__ u16 qhh[32 * 136];    // qh hi [32 b][136 r-local]
  __shared__ u16 qhl[32 * 136];    // qh lo
  __shared__ float slog[256];      // strategy logits [32 b][8 i]

  // query B-frags (bf16-exact), loop-invariant: qf[bt][ks]
  bf16x8 qf[2][8];
  #pragma unroll
  for (int bt = 0; bt < 2; ++bt)
    #pragma unroll
    for (int ks = 0; ks < 8; ++ks) {
      const float* qp = &query[(size_t)(bt * 16 + col) * H_ + ks * 32 + khi * 8];
      float4 v0 = *(const float4*)qp, v1 = *(const float4*)(qp + 4);
      bf16x8 q;
      q[0] = f2b(v0.x); q[1] = f2b(v0.y); q[2] = f2b(v0.z); q[3] = f2b(v0.w);
      q[4] = f2b(v1.x); q[5] = f2b(v1.y); q[6] = f2b(v1.z); q[7] = f2b(v1.w);
      qf[bt][ks] = q;
    }

  // strategy logits via MFMA (block 0, wave 0). A = stw rows (col<8), B = qf.
  if (f == 0 && hf == 0 && w == 0) {
    f32x4 sacc[2] = {(f32x4){0.f,0.f,0.f,0.f}, (f32x4){0.f,0.f,0.f,0.f}};
    #pragma unroll
    for (int ks = 0; ks < 8; ++ks) {
      bf16x8 a = (bf16x8){0,0,0,0,0,0,0,0};
      if (col < 8) {
        const float* sp = &stw[(size_t)col * H_ + ks * 32 + khi * 8];
        float4 v0 = *(const float4*)sp, v1 = *(const float4*)(sp + 4);
        a[0] = f2b(v0.x); a[1] = f2b(v0.y); a[2] = f2b(v0.z); a[3] = f2b(v0.w);
        a[4] = f2b(v1.x); a[5] = f2b(v1.y); a[6] = f2b(v1.z); a[7] = f2b(v1.w);
      }
      sacc[0] = MFMA(a, qf[0][ks], sacc[0]);
      sacc[1] = MFMA(a, qf[1][ks], sacc[1]);
    }
    if (khi < 2) {   // D row = i = khi*4+r (<8), col -> b
      #pragma unroll
      for (int bt = 0; bt < 2; ++bt)
        #pragma unroll
        for (int r = 0; r < 4; ++r) {
          int i = khi * 4 + r;
          slog[(bt * 16 + col) * 8 + i] = sacc[bt][r] + stb[i];
        }
    }
  }

  // ---- phase 1: qh GEMM ----
  f32x4 qacc[2] = {(f32x4){0.f,0.f,0.f,0.f}, (f32x4){0.f,0.f,0.f,0.f}};
  for (int ks = 0; ks < 8; ++ks) {
    #pragma unroll
    for (int p = 0; p < 2; ++p) {    // Wq panel: 128 r x 32 k, coalesced
      int gid = tid + 512 * p;
      int r = gid >> 3, kq = (gid & 7) * 4;
      float4 v = *(const float4*)&ipw[((size_t)(f * 768) + hf * 128 + r) * H_ + ks * 32 + kq];
      *(ushort4*)&sW[r * 40 + kq] = make_ushort4(f2b(v.x), f2b(v.y), f2b(v.z), f2b(v.w));
    }
    __syncthreads();
    bf16x8 a = *(const bf16x8*)&sW[(w * 16 + col) * 40 + khi * 8];
    qacc[0] = MFMA(a, qf[0][ks], qacc[0]);
    qacc[1] = MFMA(a, qf[1][ks], qacc[1]);
    __syncthreads();
  }
  // epilogue: + bq, hi/lo split -> qhh/qhl. lane: r = w*16+khi*4+reg, b = bt*16+col
  {
    int r0 = w * 16 + khi * 4;
    float4 bq = *(const float4*)&ipb[f * 768 + hf * 128 + r0];
    #pragma unroll
    for (int bt = 0; bt < 2; ++bt) {
      int b = bt * 16 + col;
      float v0 = qacc[bt][0] + bq.x, v1 = qacc[bt][1] + bq.y;
      float v2 = qacc[bt][2] + bq.z, v3 = qacc[bt][3] + bq.w;
      ushort4 hs = make_ushort4(f2b(v0), f2b(v1), f2b(v2), f2b(v3));
      ushort4 ls = make_ushort4(f2b(v0 - b2f(hs.x)), f2b(v1 - b2f(hs.y)),
                                f2b(v2 - b2f(hs.z)), f2b(v3 - b2f(hs.w)));
      *(ushort4*)&qhh[b * 136 + r0] = hs;
      *(ushort4*)&qhl[b * 136 + r0] = ls;
    }
  }
  __syncthreads();

  // strategy softmax (block 0, after slog complete — wave 0 wrote pre-loop,
  // all waves synced since)
  if (f == 0 && hf == 0 && tid < 32) {
    float mx = slog[tid * 8];
    #pragma unroll
    for (int i = 1; i < F_; ++i) mx = fmaxf(mx, slog[tid * 8 + i]);
    float s = 0.f, e[F_];
    #pragma unroll
    for (int i = 0; i < F_; ++i) { e[i] = __expf(slog[tid * 8 + i] - mx); s += e[i]; }
    #pragma unroll
    for (int i = 0; i < F_; ++i) strat[tid * F_ + i] = e[i] / s;
  }

  // ---- phase 2: u per head ----
  const float scale = 0.17677669529663687f;
  for (int hh = 0; hh < 4; ++hh) {
    #pragma unroll
    for (int p = 0; p < 4; ++p) {    // WkT stage: read rows coalesced, write transposed+swizzled
      int gid = tid + 512 * p;
      int d = gid >> 6, jq = (gid & 63) * 4;
      float4 v = *(const float4*)&ipw[((size_t)(f * 768 + 256) + (hf * 4 + hh) * 32 + d) * H_ + jq];
      float vv[4] = {v.x, v.y, v.z, v.w};
      #pragma unroll
      for (int e = 0; e < 4; ++e) {
        int j = jq + e;
        sW[j * 40 + (d ^ (((j >> 4) & 3) << 3))] = f2b(vv[e]);
      }
    }
    __syncthreads();
    #pragma unroll
    for (int q = 0; q < 2; ++q) {
      int jt = w * 2 + q;
      bf16x8 a = *(const bf16x8*)&sW[(jt * 16 + col) * 40 + ((khi ^ (jt & 3)) * 8)];
      #pragma unroll
      for (int bt = 0; bt < 2; ++bt) {
        int b = bt * 16 + col;
        bf16x8 bh = *(const bf16x8*)&qhh[b * 136 + hh * 32 + khi * 8];
        bf16x8 bl = *(const bf16x8*)&qhl[b * 136 + hh * 32 + khi * 8];
        f32x4 acc = (f32x4){0.f, 0.f, 0.f, 0.f};
        acc = MFMA(a, bh, acc);
        acc = MFMA(a, bl, acc);
        int j0 = jt * 16 + khi * 4;
        ushort4 us = make_ushort4(f2b(acc[0] * scale), f2b(acc[1] * scale),
                                  f2b(acc[2] * scale), f2b(acc[3] * scale));
        *(ushort4*)&u[((size_t)(b * 64) + f * 8 + hf * 4 + hh) * H_ + j0] = us;
      }
    }
    __syncthreads();
  }
}

// =============== K2N: MFMA scores -> 256-chunk softmax partials ==================
// grid (8, 32): chunk = 256 docs. 512 thr, 8 waves. Wave w: n-rows w*32..+32
// (2 M-tiles) x 64 fh. Reg-prefetched staging.
__global__ __launch_bounds__(512) void k2_stats(
    const float* __restrict__ docs, const float* __restrict__ cw,
    const u16* __restrict__ u, float* __restrict__ pm, float* __restrict__ pl)
{
  const int ns = blockIdx.x, b = blockIdx.y;
  const int n0 = ns * 256;
  const int tid = threadIdx.x, L = tid & 63, w = tid >> 6;
  const int khi = L >> 4, col = L & 15;

  __shared__ u16 sdu[256 * 72];     // docs [256 n][72 j] bf16 (j0-window of 64)
  __shared__ bf16x8 su8[64 * 9];    // u chunk [64 fh][72 j]
  __shared__ float scw[256];
  __shared__ float swred[8][64];
  __shared__ float sbm[64];

  if (tid < 256) scw[tid] = cw[b * N_ + n0 + tid];

  f32x4 acc[2][4];
  #pragma unroll
  for (int t = 0; t < 2; ++t)
    #pragma unroll
    for (int nt = 0; nt < 4; ++nt) acc[t][nt] = (f32x4){0.f, 0.f, 0.f, 0.f};

  // prefetch j0=0 docs window
  float4 dv[8];
  #pragma unroll
  for (int p = 0; p < 8; ++p) {
    int idx = tid + 512 * p;
    int n = idx >> 4, jq = (idx & 15) * 4;
    dv[p] = *(const float4*)&docs[((size_t)(b * N_) + n0 + n) * H_ + jq];
  }

  for (int jv = 0; jv < 4; ++jv) {
    const int j0 = jv * 64;
    if (jv) __syncthreads();     // previous window fully consumed
    {  // u [64][64-slice]: one bf16x8 per thread
      int fh = tid >> 3, sub = tid & 7;
      su8[fh * 9 + sub] = *(const bf16x8*)&u[((size_t)(b * 64) + fh) * H_ + j0 + sub * 8];
    }
    #pragma unroll
    for (int p = 0; p < 8; ++p) {   // stage docs window from regs
      int idx = tid + 512 * p;
      int n = idx >> 4, jq = (idx & 15) * 4;
      *(ushort4*)&sdu[n * 72 + jq] =
          make_ushort4(f2b(dv[p].x), f2b(dv[p].y), f2b(dv[p].z), f2b(dv[p].w));
    }
    if (jv < 3) {                   // prefetch next window (hides under MFMA)
      #pragma unroll
      for (int p = 0; p < 8; ++p) {
        int idx = tid + 512 * p;
        int n = idx >> 4, jq = (idx & 15) * 4;
        dv[p] = *(const float4*)&docs[((size_t)(b * N_) + n0 + n) * H_ + j0 + 64 + jq];
      }
    }
    __syncthreads();
    #pragma unroll
    for (int kk = 0; kk < 64; kk += 32) {
      bf16x8 a0 = *(const bf16x8*)&sdu[(w * 32 + col) * 72 + kk + khi * 8];
      bf16x8 a1 = *(const bf16x8*)&sdu[(w * 32 + 16 + col) * 72 + kk + khi * 8];
      #pragma unroll
      for (int nt = 0; nt < 4; ++nt) {
        bf16x8 bb = su8[(nt * 16 + col) * 9 + kk / 8 + khi];
        acc[0][nt] = MFMA(a0, bb, acc[0][nt]);
        acc[1][nt] = MFMA(a1, bb, acc[1][nt]);
      }
    }
  }
  // s = raw * cw ; chunk max / sum-exp per fh
  float cwv[2][4];
  #pragma unroll
  for (int t = 0; t < 2; ++t)
    #pragma unroll
    for (int r = 0; r < 4; ++r) cwv[t][r] = scw[w * 32 + t * 16 + khi * 4 + r];

  float mx[4];
  #pragma unroll
  for (int nt = 0; nt < 4; ++nt) {
    mx[nt] = -3.4e38f;
    #pragma unroll
    for (int t = 0; t < 2; ++t)
      #pragma unroll
      for (int r = 0; r < 4; ++r) {
        float sv = acc[t][nt][r] * cwv[t][r];
        acc[t][nt][r] = sv;
        mx[nt] = fmaxf(mx[nt], sv);
      }
    mx[nt] = fmaxf(mx[nt], __shfl_xor(mx[nt], 16, 64));
    mx[nt] = fmaxf(mx[nt], __shfl_xor(mx[nt], 32, 64));
  }
  if (L < 16) {
    #pragma unroll
    for (int nt = 0; nt < 4; ++nt) swred[w][nt * 16 + L] = mx[nt];
  }
  __syncthreads();
  if (tid < 64) {
    float m = swred[0][tid];
    #pragma unroll
    for (int ww = 1; ww < 8; ++ww) m = fmaxf(m, swred[ww][tid]);
    sbm[tid] = m;
  }
  __syncthreads();
  float ls[4];
  #pragma unroll
  for (int nt = 0; nt < 4; ++nt) {
    float bm = sbm[nt * 16 + col];
    ls[nt] = 0.f;
    #pragma unroll
    for (int t = 0; t < 2; ++t)
      #pragma unroll
      for (int r = 0; r < 4; ++r) ls[nt] += __expf(acc[t][nt][r] - bm);
    ls[nt] += __shfl_xor(ls[nt], 16, 64);
    ls[nt] += __shfl_xor(ls[nt], 32, 64);
  }
  __syncthreads();
  if (L < 16) {
    #pragma unroll
    for (int nt = 0; nt < 4; ++nt) swred[w][nt * 16 + L] = ls[nt];
  }
  __syncthreads();
  if (tid < 64) {
    float bl = 0.f;
    #pragma unroll
    for (int ww = 0; ww < 8; ++ww) bl += swred[ww][tid];
    size_t ro = (size_t)(b * 64 + tid) * NCH_ + ns;
    pm[ro] = sbm[tid];
    pl[ro] = bl;
  }
}

// =============== K4_PART: n-split register-W GEMM + atomic merge =================
// grid (8 ns, 32 b), 512 thr (8 waves). Block: n-range ns*256..+256, all 64 fh,
// all 256 j, W in registers (acc2[4][2] f32x4 / thread), 4 chunks of 64 n.
__global__ __launch_bounds__(512) void k4_part(
    const float* __restrict__ docs, const float* __restrict__ cw,
    const u16* __restrict__ u, const float* __restrict__ pm,
    const float* __restrict__ pl, float* __restrict__ wbuf)
{
  const int ns = blockIdx.x, b = blockIdx.y;
  const int n0 = ns * 256;
  const int tid = threadIdx.x, L = tid & 63, w = tid >> 6;
  const int khi = L >> 4, col = L & 15;
  const int ft = w & 3, nt0 = (w >> 2) * 2;

  __shared__ u16 sdu[64 * 264];     // docs chunk [64 n][264 j] bf16, col-swizzled
  __shared__ u16 phu[64 * 72];      // P_hi [64 fh][72 n]
  __shared__ u16 plou[64 * 72];     // P_lo
  __shared__ float sm_l[64], sl_l[64];

  if (tid < 64) {   // global m, 1/l per fh from chunk partials
    size_t ro = (size_t)(b * 64 + tid) * NCH_;
    float m = pm[ro];
    for (int cc = 1; cc < NCH_; ++cc) m = fmaxf(m, pm[ro + cc]);
    float l = 0.f;
    for (int cc = 0; cc < NCH_; ++cc) l += pl[ro + cc] * __expf(pm[ro + cc] - m);
    sm_l[tid] = m;
    sl_l[tid] = 1.f / l;
  }

  // loop-invariant u A-fragments for this wave's fh-tile ft
  bf16x8 uf[8];
  #pragma unroll
  for (int ks = 0; ks < 8; ++ks)
    uf[ks] = *(const bf16x8*)&u[((size_t)(b * 64) + ft * 16 + col) * H_ + ks * 32 + khi * 8];

  // prefetch + stage chunk 0 (swizzled store)
  float4 dv[8];
  #pragma unroll
  for (int p = 0; p < 8; ++p) {
    int idx = tid + 512 * p;
    int n = idx >> 6, jq = (idx & 63) * 4;
    dv[p] = *(const float4*)&docs[((size_t)(b * N_) + n0 + n) * H_ + jq];
  }
  #pragma unroll
  for (int p = 0; p < 8; ++p) {
    int idx = tid + 512 * p;
    int n = idx >> 6, jq = (idx & 63) * 4;
    *(ushort4*)&sdu[n * 264 + (jq ^ (((n >> 3) & 3) << 4))] =
        make_ushort4(f2b(dv[p].x), f2b(dv[p].y), f2b(dv[p].z), f2b(dv[p].w));
  }
  __syncthreads();   // staging + sm_l visible

  f32x4 acc2[4][2];
  #pragma unroll
  for (int mt = 0; mt < 4; ++mt)
    #pragma unroll
    for (int jt = 0; jt < 2; ++jt) acc2[mt][jt] = (f32x4){0.f, 0.f, 0.f, 0.f};

  for (int nc = 0; nc < 4; ++nc) {
    // issue next chunk's global loads (latency hides under MFMA phases)
    if (nc < 3) {
      #pragma unroll
      for (int p = 0; p < 8; ++p) {
        int idx = tid + 512 * p;
        int n = idx >> 6, jq = (idx & 63) * 4;
        dv[p] = *(const float4*)&docs[((size_t)(b * N_) + n0 + (nc + 1) * 64 + n) * H_ + jq];
      }
    }
    // scores: D[fh(ft)][n(nt0,nt0+1)] = u . docs^T, K=256
    f32x4 sc0 = (f32x4){0.f, 0.f, 0.f, 0.f}, sc1 = sc0;
    const int nr0 = nt0 * 16 + col, nr1 = (nt0 + 1) * 16 + col;
    const int sw0 = ((nr0 >> 3) & 3) << 4, sw1 = ((nr1 >> 3) & 3) << 4;
    #pragma unroll
    for (int ks = 0; ks < 8; ++ks) {
      bf16x8 b0 = *(const bf16x8*)&sdu[nr0 * 264 + ((ks * 32 + khi * 8) ^ sw0)];
      bf16x8 b1 = *(const bf16x8*)&sdu[nr1 * 264 + ((ks * 32 + khi * 8) ^ sw1)];
      sc0 = MFMA(uf[ks], b0, sc0);
      sc1 = MFMA(uf[ks], b1, sc1);
    }
    // P epilogue: lane holds (fh=ft*16+khi*4+r, n=nt*16+col)
    {
      int ng = n0 + nc * 64 + nt0 * 16 + col;
      float cv0 = cw[(size_t)b * N_ + ng];
      float cv1 = cw[(size_t)b * N_ + ng + 16];
      #pragma unroll
      for (int r = 0; r < 4; ++r) {
        int fh = ft * 16 + khi * 4 + r;
        float m = sm_l[fh], li = sl_l[fh];
        float p0 = __expf(sc0[r] * cv0 - m) * li * cv0;
        float p1 = __expf(sc1[r] * cv1 - m) * li * cv1;
        u16 h0 = f2b(p0), h1 = f2b(p1);
        phu [fh * 72 + nt0 * 16 + col]       = h0;
        plou[fh * 72 + nt0 * 16 + col]       = f2b(p0 - b2f(h0));
        phu [fh * 72 + (nt0 + 1) * 16 + col] = h1;
        plou[fh * 72 + (nt0 + 1) * 16 + col] = f2b(p1 - b2f(h1));
      }
    }
    __syncthreads();   // P visible to all waves; sdu intact

    // W[fh][j] += sum_n P[fh][n] * docs[n][j]; wave owns j = w*32 + jt*16 + col
    #pragma unroll
    for (int kk = 0; kk < 2; ++kk) {
      #pragma unroll
      for (int jt = 0; jt < 2; ++jt) {
        int j = w * 32 + jt * 16 + col;
        bf16x8 bb;
        #pragma unroll
        for (int jj = 0; jj < 8; ++jj)
          bb[jj] = (short)sdu[(kk * 32 + khi * 8 + jj) * 264 + (j ^ (khi << 4))];
        #pragma unroll
        for (int mt = 0; mt < 4; ++mt) {
          bf16x8 ah = *(const bf16x8*)&phu [(mt * 16 + col) * 72 + kk * 32 + khi * 8];
          bf16x8 al = *(const bf16x8*)&plou[(mt * 16 + col) * 72 + kk * 32 + khi * 8];
          acc2[mt][jt] = MFMA(ah, bb, acc2[mt][jt]);
          acc2[mt][jt] = MFMA(al, bb, acc2[mt][jt]);
        }
      }
    }
    __syncthreads();   // all reads of sdu/P done

    if (nc < 3) {      // stage next chunk from regs
      #pragma unroll
      for (int p = 0; p < 8; ++p) {
        int idx = tid + 512 * p;
        int n = idx >> 6, jq = (idx & 63) * 4;
        *(ushort4*)&sdu[n * 264 + (jq ^ (((n >> 3) & 3) << 4))] =
            make_ushort4(f2b(dv[p].x), f2b(dv[p].y), f2b(dv[p].z), f2b(dv[p].w));
      }
      __syncthreads();
    }
  }
  // merge partial W (one atomic per element; 8 adds per address across ns)
  #pragma unroll
  for (int mt = 0; mt < 4; ++mt)
    #pragma unroll
    for (int jt = 0; jt < 2; ++jt)
      #pragma unroll
      for (int r = 0; r < 4; ++r) {
        int fh = mt * 16 + khi * 4 + r;
        int j = w * 32 + jt * 16 + col;
        atomicAdd(&wbuf[((size_t)(b * 64) + fh) * H_ + j], acc2[mt][jt][r]);
      }
}

// =============== KT: meta -> bf16 metaT[s][x][r] = meta[s][r][x] =================
__global__ __launch_bounds__(256) void kt_meta(
    const float* __restrict__ meta, u16* __restrict__ metaT)
{
  const int s = blockIdx.x, xg = blockIdx.y;   // s<3, xg<8
  const int x0 = xg * 32;
  const int tid = threadIdx.x;
  __shared__ u16 sT[32 * 264];                 // [32 x][264 r] transposed tile
  #pragma unroll
  for (int p = 0; p < 8; ++p) {                // load 256 r x 32 x, coalesced
    int idx = tid + 256 * p;
    int r = idx >> 3, xq = (idx & 7) * 4;
    float4 v = *(const float4*)&meta[((size_t)(s * 256) + r) * 256 + x0 + xq];
    sT[(xq + 0) * 264 + r] = f2b(v.x);
    sT[(xq + 1) * 264 + r] = f2b(v.y);
    sT[(xq + 2) * 264 + r] = f2b(v.z);
    sT[(xq + 3) * 264 + r] = f2b(v.w);
  }
  __syncthreads();
  #pragma unroll
  for (int p = 0; p < 4; ++p) {                // store rows of metaT, 16B chunks
    int idx = tid + 256 * p;
    int x = idx >> 5, rq = (idx & 31) * 8;
    bf16x8 v = *(bf16x8*)&sT[x * 264 + rq];
    *(bf16x8*)&metaT[((size_t)(s * 256) + x0 + x) * 256 + rq] = v;
  }
}

// =============== K5: MFMA chain ctx -> ho0 -> 3 meta steps =======================
// grid 16 = (f 8) x (b-tile 2 of 16 b), 512 threads (8 waves).
__global__ __launch_bounds__(512) void k5_mfma(
    const float* __restrict__ ipw, const float* __restrict__ ipb,
    const float* __restrict__ opw, const float* __restrict__ opb,
    const u16* __restrict__ metaT, const float* __restrict__ wbuf,
    float* __restrict__ ho)
{
  const int f = blockIdx.x & 7, b0 = (blockIdx.x >> 3) * 16;
  const int tid = threadIdx.x, L = tid & 63, w = tid >> 6;   // w = wave 0..7
  const int khi = L >> 4, col = L & 15;

  __shared__ char smem[57856];
  u16* sWvP  = (u16*)(smem);             // ctx: [256 (h,d)][40]
  u16* sWhiP = (u16*)(smem + 20480);     // ctx: [128 (h,b)][40]
  u16* sWloP = (u16*)(smem + 30720);
  u16* sWo   = (u16*)(smem);             // ho:  [256 r][40]
  u16* XBh   = (u16*)(smem + 20480);     // [16 b][264 c]
  u16* XBl   = (u16*)(smem + 28928);
  u16* XAh   = (u16*)(smem + 40960);
  u16* XAl   = (u16*)(smem + 49408);

  // ---- ctx: per-ks panels of Wv (all h) and w (all h, hi/lo) ----
  f32x4 cacc0 = (f32x4){0.f, 0.f, 0.f, 0.f};
  f32x4 cacc1 = (f32x4){0.f, 0.f, 0.f, 0.f};
  for (int ks = 0; ks < 8; ++ks) {
    #pragma unroll
    for (int p = 0; p < 4; ++p) {        // Wv panel: 256 rows (h*32+d) x 32 c
      int idx = tid + 512 * p;
      int r = idx >> 3, cq = (idx & 7) * 4;
      float4 v = *(const float4*)&ipw[((size_t)(f * 768 + 512) + r) * 256 + ks * 32 + cq];
      *(ushort4*)&sWvP[r * 40 + cq] = make_ushort4(f2b(v.x), f2b(v.y), f2b(v.z), f2b(v.w));
    }
    #pragma unroll
    for (int p = 0; p < 2; ++p) {        // w panel: 128 rows (h*16+b) x 32 j, hi/lo
      int idx = tid + 512 * p;
      int rr = idx >> 3, cq = (idx & 7) * 4;
      int h = rr >> 4, b = rr & 15;
      float4 v = *(const float4*)&wbuf[((size_t)((b0 + b) * 64) + f * 8 + h) * 256 + ks * 32 + cq];
      u16 hx = f2b(v.x), hy = f2b(v.y), hz = f2b(v.z), hw2 = f2b(v.w);
      *(ushort4*)&sWhiP[rr * 40 + cq] = make_ushort4(hx, hy, hz, hw2);
      *(ushort4*)&sWloP[rr * 40 + cq] = make_ushort4(
          f2b(v.x - b2f(hx)), f2b(v.y - b2f(hy)), f2b(v.z - b2f(hz)), f2b(v.w - b2f(hw2)));
    }
    __syncthreads();
    bf16x8 bh = *(bf16x8*)&sWhiP[(w * 16 + col) * 40 + khi * 8];
    bf16x8 bl = *(bf16x8*)&sWloP[(w * 16 + col) * 40 + khi * 8];
    bf16x8 a0 = *(bf16x8*)&sWvP[(w * 32 + col) * 40 + khi * 8];
    bf16x8 a1 = *(bf16x8*)&sWvP[(w * 32 + 16 + col) * 40 + khi * 8];
    cacc0 = MFMA(a0, bh, cacc0); cacc0 = MFMA(a0, bl, cacc0);
    cacc1 = MFMA(a1, bh, cacc1); cacc1 = MFMA(a1, bl, cacc1);
    __syncthreads();
  }
  // ctx + bv -> XA hi/lo. lane owns (d = mt*16+khi*4+r, b = col) for h = w.
  #pragma unroll
  for (int mt = 0; mt < 2; ++mt) {
    f32x4 cv = mt ? cacc1 : cacc0;
    #pragma unroll
    for (int r = 0; r < 4; ++r) {
      int d = mt * 16 + khi * 4 + r;
      float vv = cv[r] + ipb[f * 768 + 512 + w * 32 + d];
      u16 hi = f2b(vv);
      XAh[col * 264 + w * 32 + d] = hi;
      XAl[col * 264 + w * 32 + d] = f2b(vv - b2f(hi));
    }
  }

  // ---- ho0: D[b][x] = ctx . Wo^T + bo ; waves own x-tiles (w*2+q)*16 ----
  f32x4 hr0, hr1;
  {
    float bo0 = opb[f * 256 + (w * 2 + 0) * 16 + col];
    float bo1 = opb[f * 256 + (w * 2 + 1) * 16 + col];
    hr0 = (f32x4){bo0, bo0, bo0, bo0};
    hr1 = (f32x4){bo1, bo1, bo1, bo1};
  }
  for (int ks = 0; ks < 8; ++ks) {
    #pragma unroll
    for (int p = 0; p < 4; ++p) {        // Wo panel: 256 r x 32 c
      int idx = tid + 512 * p;
      int r = idx >> 3, cq = (idx & 7) * 4;
      float4 v = *(const float4*)&opw[((size_t)(f * 256) + r) * 256 + ks * 32 + cq];
      *(ushort4*)&sWo[r * 40 + cq] = make_ushort4(f2b(v.x), f2b(v.y), f2b(v.z), f2b(v.w));
    }
    __syncthreads();
    bf16x8 ah  = *(bf16x8*)&XAh[col * 264 + ks * 32 + khi * 8];
    bf16x8 al  = *(bf16x8*)&XAl[col * 264 + ks * 32 + khi * 8];
    bf16x8 bw0 = *(bf16x8*)&sWo[((w * 2 + 0) * 16 + col) * 40 + khi * 8];
    bf16x8 bw1 = *(bf16x8*)&sWo[((w * 2 + 1) * 16 + col) * 40 + khi * 8];
    hr0 = MFMA(ah, bw0, hr0); hr0 = MFMA(al, bw0, hr0);
    hr1 = MFMA(ah, bw1, hr1); hr1 = MFMA(al, bw1, hr1);
    __syncthreads();
  }

  // spill ho hi/lo to LDS buffer (Oh/Ol); residual fp32 stays in hr0/hr1
  auto spill = [&](u16* Oh, u16* Ol) {
    #pragma unroll
    for (int q = 0; q < 2; ++q) {
      f32x4 hv = q ? hr1 : hr0;
      int x = (w * 2 + q) * 16 + col;
      #pragma unroll
      for (int r = 0; r < 4; ++r) {
        u16 hi = f2b(hv[r]);
        Oh[(khi * 4 + r) * 264 + x] = hi;
        Ol[(khi * 4 + r) * 264 + x] = f2b(hv[r] - b2f(hi));
      }
    }
  };
  // one meta step: hr += (ho_s) @ meta[s], A = ho_s hi/lo, B = metaT (exact bf16)
  auto meta_mm = [&](const u16* Ah_, const u16* Al_, int s) {
    f32x4 n0 = hr0, n1 = hr1;
    #pragma unroll
    for (int ks = 0; ks < 8; ++ks) {
      bf16x8 ah = *(const bf16x8*)&Ah_[col * 264 + ks * 32 + khi * 8];
      bf16x8 al = *(const bf16x8*)&Al_[col * 264 + ks * 32 + khi * 8];
      const u16* mrow = &metaT[((size_t)(s * 256) + (w * 2) * 16 + col) * 256 + ks * 32 + khi * 8];
      bf16x8 m0 = *(const bf16x8*)mrow;
      bf16x8 m1 = *(const bf16x8*)(mrow + 16 * 256);
      n0 = MFMA(ah, m0, n0); n0 = MFMA(al, m0, n0);
      n1 = MFMA(ah, m1, n1); n1 = MFMA(al, m1, n1);
    }
    hr0 = n0; hr1 = n1;
  };

  spill(XBh, XBl);            // ho0
  __syncthreads();
  meta_mm(XBh, XBl, 0);
  spill(XAh, XAl);
  __syncthreads();
  meta_mm(XAh, XAl, 1);
  spill(XBh, XBl);
  __syncthreads();
  meta_mm(XBh, XBl, 2);

  // final ho (fp32 residual accumulator) -> global [F][B][H]
  #pragma unroll
  for (int q = 0; q < 2; ++q) {
    f32x4 hv = q ? hr1 : hr0;
    int x = (w * 2 + q) * 16 + col;
    #pragma unroll
    for (int r = 0; r < 4; ++r) {
      int b = khi * 4 + r;
      ho[((size_t)(f * B_) + b0 + b) * 256 + x] = hv[r];
    }
  }
}

// =============== K6: strategy combine -> fp32 out ================================
__global__ __launch_bounds__(256) void k6_combine(
    const float* __restrict__ ho, const float* __restrict__ strat,
    float* __restrict__ out)
{
  const int b = blockIdx.x;
  const int tid = threadIdx.x;
  float acc = 0.f;
  #pragma unroll
  for (int f = 0; f < F_; ++f)
    acc += strat[b * F_ + f] * ho[((size_t)(f * B_) + b) * H_ + tid];
  out[b * H_ + tid] = acc;
}

extern "C" void kernel_launch(void* const* d_in, const int* in_sizes, int n_in,
                              void* d_out, int out_size, void* d_ws, size_t ws_size,
                              hipStream_t stream) {
  const float* query = (const float*)d_in[0];
  const float* docs  = (const float*)d_in[1];
  const float* cw    = (const float*)d_in[2];
  // d_in[3] context_history: unused by the reference
  const float* ipw   = (const float*)d_in[4];
  const float* ipb   = (const float*)d_in[5];
  const float* opw   = (const float*)d_in[6];
  const float* opb   = (const float*)d_in[7];
  const float* stw   = (const float*)d_in[8];
  const float* stb   = (const float*)d_in[9];
  const float* meta  = (const float*)d_in[10];
  float* out = (float*)d_out;

  char* base = (char*)d_ws;
  u16*   u     = (u16*)(base + UB_U);
  u16*   metaT = (u16*)(base + UB_U);   // overlays u; written only after k4_part
  float* wbuf  = (float*)(base + UB_W);
  float* pm    = (float*)(base + UB_PM);
  float* pl    = (float*)(base + UB_PL);
  float* strat = (float*)(base + UB_STRAT);
  float* ho    = (float*)(base + UB_HO);

  hipMemsetAsync(wbuf, 0, (size_t)B_ * FH_ * H_ * sizeof(float), stream);
  k1_mfma<<<dim3(16), 512, 0, stream>>>(query, ipw, ipb, stw, stb, u, strat);
  k2_stats<<<dim3(NCH_, B_), 512, 0, stream>>>(docs, cw, u, pm, pl);
  k4_part<<<dim3(NCH_, B_), 512, 0, stream>>>(docs, cw, u, pm, pl, wbuf);
  kt_meta<<<dim3(3, 8), 256, 0, stream>>>(meta, metaT);
  k5_mfma<<<dim3(16), 512, 0, stream>>>(ipw, ipb, opw, opb, metaT, wbuf, ho);
  k6_combine<<<dim3(B_), 256, 0, stream>>>(ho, strat, out);
}

// Round 5
// 195.588 us; speedup vs baseline: 1.5095x; 1.0693x over previous
//
#include <hip/hip_runtime.h>
#include <hip/hip_bf16.h>

// MetaAdaptiveFusion: B=32, N=2048, H=256, F=8, NH=8, dh=32, 3 meta steps.
// Inputs: fp32 buffers holding bf16-quantized values -> bf16 casts of INPUTS are
// LOSSLESS. Computed activations (qh, w, ctx, ho, e*cw) are hi/lo-split
// compensated bf16; residual carries stay fp32. Output fp32.
//
// R12: shift-free softmax restructure. Scores s=(u.docs)*cw have |s|<~0.4
// (0.02-scaled weights), so exp(s) needs no max-subtraction (softmax is
// shift-invariant; removing the shift changes only ~1e-7 relative rounding).
// Normalization 1/l is linear -> applied to W in k5 staging, not per-P.
// => k2_stats (second 64MB docs pass + pm/pl) DELETED. k4_one: single docs
// pass, W_unnorm += (exp(s)*cw).docs reg-accum + atomic merge; l summed via
// register accum + 16-lane shuffle + global atomics (lbuf). kt fused into k1
// (grid 40); k6 fused into k5 (strat-weighted atomicAdd into zeroed out).
// Pipeline: memset(out); memset(wbuf+lbuf); k1_fused; k4_one; k5_mfma.
// Fragment layouts per verified gfx950 conventions (A: m=lane&15,
// k=(lane>>4)*8+j ; B: n=lane&15 same k ; D: col=lane&15, row=(lane>>4)*4+reg).

#define B_ 32
#define N_ 2048
#define H_ 256
#define F_ 8
#define FH_ 64
#define NCH_ 8   // 8 n-split blocks of 256 docs

typedef unsigned short u16;
typedef __attribute__((ext_vector_type(8))) short bf16x8;   // 8 bf16 (4 VGPRs)
typedef __attribute__((ext_vector_type(4))) float f32x4;
#define MFMA(a, b, c) __builtin_amdgcn_mfma_f32_16x16x32_bf16((a), (b), (c), 0, 0, 0)

__device__ __forceinline__ u16 f2b(float x) {   // fp32 -> bf16 bits, RNE
  unsigned u = __builtin_bit_cast(unsigned, x);
  return (u16)((u + 0x7fffu + ((u >> 16) & 1u)) >> 16);
}
__device__ __forceinline__ float b2f(u16 h) {
  unsigned u = ((unsigned)h) << 16;
  return __builtin_bit_cast(float, u);
}

// ---- ws byte layout (<= 3,548,160 B; 3,687,424 proven safe in R6) ----
static constexpr size_t UB_U     = 0;          // u16 [B][FH][H]    1,048,576
static constexpr size_t UB_W     = 1048576;    // f32 [B][FH][H]    2,097,152
static constexpr size_t UB_L     = 3145728;    // f32 [B][FH]           8,192
static constexpr size_t UB_STRAT = 3153920;    // f32 [B][F]            1,024
static constexpr size_t UB_MT    = 3154944;    // u16 [3][256][256]   393,216

// =============== K1_FUSED: MFMA qh -> u, strategy  |  metaT transpose ============
// grid 40, 512 thr. Blocks 0..15: (f 8) x (h-half 2) qh/u/strategy.
// Blocks 16..39: (s 3) x (xg 8) meta -> bf16 metaT[s][x][r] (meta bf16-exact).
__global__ __launch_bounds__(512) void k1_fused(
    const float* __restrict__ query, const float* __restrict__ ipw,
    const float* __restrict__ ipb, const float* __restrict__ stw,
    const float* __restrict__ stb, const float* __restrict__ meta,
    u16* __restrict__ u, u16* __restrict__ metaT, float* __restrict__ strat)
{
  const int tid = threadIdx.x, L = tid & 63, w = tid >> 6;
  const int khi = L >> 4, col = L & 15;

  if (blockIdx.x >= 16) {   // ---- kt part: metaT ----
    const int bid2 = blockIdx.x - 16;
    const int s = bid2 >> 3, x0 = (bid2 & 7) * 32;
    __shared__ u16 sT[32 * 264];               // [32 x][264 r]
    #pragma unroll
    for (int p = 0; p < 4; ++p) {              // load 256 r x 32 x, coalesced
      int idx = tid + 512 * p;
      int r = idx >> 3, xq = (idx & 7) * 4;
      float4 v = *(const float4*)&meta[((size_t)(s * 256) + r) * 256 + x0 + xq];
      sT[(xq + 0) * 264 + r] = f2b(v.x);
      sT[(xq + 1) * 264 + r] = f2b(v.y);
      sT[(xq + 2) * 264 + r] = f2b(v.z);
      sT[(xq + 3) * 264 + r] = f2b(v.w);
    }
    __syncthreads();
    #pragma unroll
    for (int p = 0; p < 2; ++p) {              // store rows of metaT, 16B chunks
      int idx = tid + 512 * p;
      int x = idx >> 5, rq = (idx & 31) * 8;
      bf16x8 v = *(bf16x8*)&sT[x * 264 + rq];
      *(bf16x8*)&metaT[((size_t)(s * 256) + x0 + x) * 256 + rq] = v;
    }
    return;
  }

  // ---- k1 part ----
  const int f = blockIdx.x >> 1, hf = blockIdx.x & 1;
  __shared__ u16 sW[256 * 40];     // phase1: Wq panel [128][40]; phase2: WkT [256 j][40 d-swz]
  __shared__ u16 qhh[32 * 136];    // qh hi [32 b][136 r-local]
  __shared__ u16 qhl[32 * 136];    // qh lo
  __shared__ float slog[256];      // strategy logits [32 b][8 i]

  // query B-frags (bf16-exact), loop-invariant: qf[bt][ks]
  bf16x8 qf[2][8];
  #pragma unroll
  for (int bt = 0; bt < 2; ++bt)
    #pragma unroll
    for (int ks = 0; ks < 8; ++ks) {
      const float* qp = &query[(size_t)(bt * 16 + col) * H_ + ks * 32 + khi * 8];
      float4 v0 = *(const float4*)qp, v1 = *(const float4*)(qp + 4);
      bf16x8 q;
      q[0] = f2b(v0.x); q[1] = f2b(v0.y); q[2] = f2b(v0.z); q[3] = f2b(v0.w);
      q[4] = f2b(v1.x); q[5] = f2b(v1.y); q[6] = f2b(v1.z); q[7] = f2b(v1.w);
      qf[bt][ks] = q;
    }

  // strategy logits via MFMA (block 0, wave 0). A = stw rows (col<8), B = qf.
  if (f == 0 && hf == 0 && w == 0) {
    f32x4 sacc[2] = {(f32x4){0.f,0.f,0.f,0.f}, (f32x4){0.f,0.f,0.f,0.f}};
    #pragma unroll
    for (int ks = 0; ks < 8; ++ks) {
      bf16x8 a = (bf16x8){0,0,0,0,0,0,0,0};
      if (col < 8) {
        const float* sp = &stw[(size_t)col * H_ + ks * 32 + khi * 8];
        float4 v0 = *(const float4*)sp, v1 = *(const float4*)(sp + 4);
        a[0] = f2b(v0.x); a[1] = f2b(v0.y); a[2] = f2b(v0.z); a[3] = f2b(v0.w);
        a[4] = f2b(v1.x); a[5] = f2b(v1.y); a[6] = f2b(v1.z); a[7] = f2b(v1.w);
      }
      sacc[0] = MFMA(a, qf[0][ks], sacc[0]);
      sacc[1] = MFMA(a, qf[1][ks], sacc[1]);
    }
    if (khi < 2) {   // D row = i = khi*4+r (<8), col -> b
      #pragma unroll
      for (int bt = 0; bt < 2; ++bt)
        #pragma unroll
        for (int r = 0; r < 4; ++r) {
          int i = khi * 4 + r;
          slog[(bt * 16 + col) * 8 + i] = sacc[bt][r] + stb[i];
        }
    }
  }

  // ---- phase 1: qh GEMM ----
  f32x4 qacc[2] = {(f32x4){0.f,0.f,0.f,0.f}, (f32x4){0.f,0.f,0.f,0.f}};
  for (int ks = 0; ks < 8; ++ks) {
    #pragma unroll
    for (int p = 0; p < 2; ++p) {    // Wq panel: 128 r x 32 k, coalesced
      int gid = tid + 512 * p;
      int r = gid >> 3, kq = (gid & 7) * 4;
      float4 v = *(const float4*)&ipw[((size_t)(f * 768) + hf * 128 + r) * H_ + ks * 32 + kq];
      *(ushort4*)&sW[r * 40 + kq] = make_ushort4(f2b(v.x), f2b(v.y), f2b(v.z), f2b(v.w));
    }
    __syncthreads();
    bf16x8 a = *(const bf16x8*)&sW[(w * 16 + col) * 40 + khi * 8];
    qacc[0] = MFMA(a, qf[0][ks], qacc[0]);
    qacc[1] = MFMA(a, qf[1][ks], qacc[1]);
    __syncthreads();
  }
  // epilogue: + bq, hi/lo split -> qhh/qhl. lane: r = w*16+khi*4+reg, b = bt*16+col
  {
    int r0 = w * 16 + khi * 4;
    float4 bq = *(const float4*)&ipb[f * 768 + hf * 128 + r0];
    #pragma unroll
    for (int bt = 0; bt < 2; ++bt) {
      int b = bt * 16 + col;
      float v0 = qacc[bt][0] + bq.x, v1 = qacc[bt][1] + bq.y;
      float v2 = qacc[bt][2] + bq.z, v3 = qacc[bt][3] + bq.w;
      ushort4 hs = make_ushort4(f2b(v0), f2b(v1), f2b(v2), f2b(v3));
      ushort4 ls = make_ushort4(f2b(v0 - b2f(hs.x)), f2b(v1 - b2f(hs.y)),
                                f2b(v2 - b2f(hs.z)), f2b(v3 - b2f(hs.w)));
      *(ushort4*)&qhh[b * 136 + r0] = hs;
      *(ushort4*)&qhl[b * 136 + r0] = ls;
    }
  }
  __syncthreads();

  // strategy softmax (block 0; slog written by wave 0, all waves synced since)
  if (f == 0 && hf == 0 && tid < 32) {
    float mx = slog[tid * 8];
    #pragma unroll
    for (int i = 1; i < F_; ++i) mx = fmaxf(mx, slog[tid * 8 + i]);
    float s = 0.f, e[F_];
    #pragma unroll
    for (int i = 0; i < F_; ++i) { e[i] = __expf(slog[tid * 8 + i] - mx); s += e[i]; }
    #pragma unroll
    for (int i = 0; i < F_; ++i) strat[tid * F_ + i] = e[i] / s;
  }

  // ---- phase 2: u per head ----
  const float scale = 0.17677669529663687f;
  for (int hh = 0; hh < 4; ++hh) {
    #pragma unroll
    for (int p = 0; p < 4; ++p) {    // WkT stage: read rows coalesced, write transposed+swizzled
      int gid = tid + 512 * p;
      int d = gid >> 6, jq = (gid & 63) * 4;
      float4 v = *(const float4*)&ipw[((size_t)(f * 768 + 256) + (hf * 4 + hh) * 32 + d) * H_ + jq];
      float vv[4] = {v.x, v.y, v.z, v.w};
      #pragma unroll
      for (int e = 0; e < 4; ++e) {
        int j = jq + e;
        sW[j * 40 + (d ^ (((j >> 4) & 3) << 3))] = f2b(vv[e]);
      }
    }
    __syncthreads();
    #pragma unroll
    for (int q = 0; q < 2; ++q) {
      int jt = w * 2 + q;
      bf16x8 a = *(const bf16x8*)&sW[(jt * 16 + col) * 40 + ((khi ^ (jt & 3)) * 8)];
      #pragma unroll
      for (int bt = 0; bt < 2; ++bt) {
        int b = bt * 16 + col;
        bf16x8 bh = *(const bf16x8*)&qhh[b * 136 + hh * 32 + khi * 8];
        bf16x8 bl = *(const bf16x8*)&qhl[b * 136 + hh * 32 + khi * 8];
        f32x4 acc = (f32x4){0.f, 0.f, 0.f, 0.f};
        acc = MFMA(a, bh, acc);
        acc = MFMA(a, bl, acc);
        int j0 = jt * 16 + khi * 4;
        ushort4 us = make_ushort4(f2b(acc[0] * scale), f2b(acc[1] * scale),
                                  f2b(acc[2] * scale), f2b(acc[3] * scale));
        *(ushort4*)&u[((size_t)(b * 64) + f * 8 + hf * 4 + hh) * H_ + j0] = us;
      }
    }
    __syncthreads();
  }
}

// =============== K4_ONE: single docs pass, shift-free exp, W + l =================
// grid (8 ns, 32 b), 512 thr (8 waves). Block: n-range ns*256..+256, all 64 fh,
// all 256 j. W_unnorm in registers (acc2[4][2] f32x4/thread), 4 chunks of 64 n.
// e = exp((u.docs)*cw) (|score|<~0.4 -> no shift needed); W-weight = e*cw hi/lo;
// l[b][fh] += sum_n e via register accum + 16-lane shuffle + global atomics.
// Scores: wave w -> (ft=w&3 fh-tile, nt0=(w>>2)*2 n-tiles), u in regs.
// W: wave w -> j-slice w*32..+32. sdu col XOR-swizzle ((n>>3)&3)<<4.
__global__ __launch_bounds__(512) void k4_one(
    const float* __restrict__ docs, const float* __restrict__ cw,
    const u16* __restrict__ u, float* __restrict__ wbuf, float* __restrict__ lbuf)
{
  const int ns = blockIdx.x, b = blockIdx.y;
  const int n0 = ns * 256;
  const int tid = threadIdx.x, L = tid & 63, w = tid >> 6;
  const int khi = L >> 4, col = L & 15;
  const int ft = w & 3, nt0 = (w >> 2) * 2;

  __shared__ u16 sdu[64 * 264];     // docs chunk [64 n][264 j] bf16, col-swizzled
  __shared__ u16 phu[64 * 72];      // (e*cw)_hi [64 fh][72 n]
  __shared__ u16 plou[64 * 72];     // (e*cw)_lo

  // loop-invariant u A-fragments for this wave's fh-tile ft
  bf16x8 uf[8];
  #pragma unroll
  for (int ks = 0; ks < 8; ++ks)
    uf[ks] = *(const bf16x8*)&u[((size_t)(b * 64) + ft * 16 + col) * H_ + ks * 32 + khi * 8];

  // prefetch + stage chunk 0 (swizzled store)
  float4 dv[8];
  #pragma unroll
  for (int p = 0; p < 8; ++p) {
    int idx = tid + 512 * p;
    int n = idx >> 6, jq = (idx & 63) * 4;
    dv[p] = *(const float4*)&docs[((size_t)(b * N_) + n0 + n) * H_ + jq];
  }
  #pragma unroll
  for (int p = 0; p < 8; ++p) {
    int idx = tid + 512 * p;
    int n = idx >> 6, jq = (idx & 63) * 4;
    *(ushort4*)&sdu[n * 264 + (jq ^ (((n >> 3) & 3) << 4))] =
        make_ushort4(f2b(dv[p].x), f2b(dv[p].y), f2b(dv[p].z), f2b(dv[p].w));
  }
  __syncthreads();

  f32x4 acc2[4][2];
  #pragma unroll
  for (int mt = 0; mt < 4; ++mt)
    #pragma unroll
    for (int jt = 0; jt < 2; ++jt) acc2[mt][jt] = (f32x4){0.f, 0.f, 0.f, 0.f};
  float eacc[4] = {0.f, 0.f, 0.f, 0.f};

  for (int nc = 0; nc < 4; ++nc) {
    // issue next chunk's global loads (latency hides under MFMA phases)
    if (nc < 3) {
      #pragma unroll
      for (int p = 0; p < 8; ++p) {
        int idx = tid + 512 * p;
        int n = idx >> 6, jq = (idx & 63) * 4;
        dv[p] = *(const float4*)&docs[((size_t)(b * N_) + n0 + (nc + 1) * 64 + n) * H_ + jq];
      }
    }
    // scores: D[fh(ft)][n(nt0,nt0+1)] = u . docs^T, K=256
    f32x4 sc0 = (f32x4){0.f, 0.f, 0.f, 0.f}, sc1 = sc0;
    const int nr0 = nt0 * 16 + col, nr1 = (nt0 + 1) * 16 + col;
    const int sw0 = ((nr0 >> 3) & 3) << 4, sw1 = ((nr1 >> 3) & 3) << 4;
    #pragma unroll
    for (int ks = 0; ks < 8; ++ks) {
      bf16x8 b0 = *(const bf16x8*)&sdu[nr0 * 264 + ((ks * 32 + khi * 8) ^ sw0)];
      bf16x8 b1 = *(const bf16x8*)&sdu[nr1 * 264 + ((ks * 32 + khi * 8) ^ sw1)];
      sc0 = MFMA(uf[ks], b0, sc0);
      sc1 = MFMA(uf[ks], b1, sc1);
    }
    // epilogue: e = exp(s*cw); weight = e*cw hi/lo; l-accum. lane: (fh, n=nt*16+col)
    {
      int ng = n0 + nc * 64 + nt0 * 16 + col;
      float cv0 = cw[(size_t)b * N_ + ng];
      float cv1 = cw[(size_t)b * N_ + ng + 16];
      #pragma unroll
      for (int r = 0; r < 4; ++r) {
        int fh = ft * 16 + khi * 4 + r;
        float ex0 = __expf(sc0[r] * cv0);
        float ex1 = __expf(sc1[r] * cv1);
        eacc[r] += ex0 + ex1;
        float p0 = ex0 * cv0, p1 = ex1 * cv1;
        u16 h0 = f2b(p0), h1 = f2b(p1);
        phu [fh * 72 + nt0 * 16 + col]       = h0;
        plou[fh * 72 + nt0 * 16 + col]       = f2b(p0 - b2f(h0));
        phu [fh * 72 + (nt0 + 1) * 16 + col] = h1;
        plou[fh * 72 + (nt0 + 1) * 16 + col] = f2b(p1 - b2f(h1));
      }
    }
    __syncthreads();   // weights visible to all waves; sdu intact

    // W[fh][j] += sum_n weight[fh][n] * docs[n][j]; wave owns j = w*32+jt*16+col
    #pragma unroll
    for (int kk = 0; kk < 2; ++kk) {
      #pragma unroll
      for (int jt = 0; jt < 2; ++jt) {
        int j = w * 32 + jt * 16 + col;
        bf16x8 bb;
        #pragma unroll
        for (int jj = 0; jj < 8; ++jj)
          bb[jj] = (short)sdu[(kk * 32 + khi * 8 + jj) * 264 + (j ^ (khi << 4))];
        #pragma unroll
        for (int mt = 0; mt < 4; ++mt) {
          bf16x8 ah = *(const bf16x8*)&phu [(mt * 16 + col) * 72 + kk * 32 + khi * 8];
          bf16x8 al = *(const bf16x8*)&plou[(mt * 16 + col) * 72 + kk * 32 + khi * 8];
          acc2[mt][jt] = MFMA(ah, bb, acc2[mt][jt]);
          acc2[mt][jt] = MFMA(al, bb, acc2[mt][jt]);
        }
      }
    }
    __syncthreads();   // all reads of sdu/weights done

    if (nc < 3) {      // stage next chunk from regs
      #pragma unroll
      for (int p = 0; p < 8; ++p) {
        int idx = tid + 512 * p;
        int n = idx >> 6, jq = (idx & 63) * 4;
        *(ushort4*)&sdu[n * 264 + (jq ^ (((n >> 3) & 3) << 4))] =
            make_ushort4(f2b(dv[p].x), f2b(dv[p].y), f2b(dv[p].z), f2b(dv[p].w));
      }
      __syncthreads();
    }
  }
  // merge partial W (one atomic per element; 8 adds per address across ns)
  #pragma unroll
  for (int mt = 0; mt < 4; ++mt)
    #pragma unroll
    for (int jt = 0; jt < 2; ++jt)
      #pragma unroll
      for (int r = 0; r < 4; ++r) {
        int fh = mt * 16 + khi * 4 + r;
        int j = w * 32 + jt * 16 + col;
        atomicAdd(&wbuf[((size_t)(b * 64) + fh) * H_ + j], acc2[mt][jt][r]);
      }
  // l partials: reduce over col (16 lanes), one atomic per (khi,r) lane group
  #pragma unroll
  for (int r = 0; r < 4; ++r) {
    float e = eacc[r];
    e += __shfl_xor(e, 1, 64);
    e += __shfl_xor(e, 2, 64);
    e += __shfl_xor(e, 4, 64);
    e += __shfl_xor(e, 8, 64);
    if (col == 0)
      atomicAdd(&lbuf[(size_t)(b * 64) + ft * 16 + khi * 4 + r], e);
  }
}

// =============== K5: MFMA chain ctx -> ho0 -> 3 meta steps -> out ================
// grid 16 = (f 8) x (b-tile 2 of 16 b), 512 threads (8 waves).
// w-panel staging scales wbuf by 1/l[b][fh] (softmax normalization, linear).
// Final epilogue: out[b][x] += strat[b][f] * ho (k6 fused; out pre-zeroed).
__global__ __launch_bounds__(512) void k5_mfma(
    const float* __restrict__ ipw, const float* __restrict__ ipb,
    const float* __restrict__ opw, const float* __restrict__ opb,
    const u16* __restrict__ metaT, const float* __restrict__ wbuf,
    const float* __restrict__ lbuf, const float* __restrict__ strat,
    float* __restrict__ out)
{
  const int f = blockIdx.x & 7, b0 = (blockIdx.x >> 3) * 16;
  const int tid = threadIdx.x, L = tid & 63, w = tid >> 6;   // w = wave 0..7
  const int khi = L >> 4, col = L & 15;

  __shared__ char smem[57856];
  __shared__ float sli[128];             // 1/l for rr = (h<<4)|b
  u16* sWvP  = (u16*)(smem);             // ctx: [256 (h,d)][40]
  u16* sWhiP = (u16*)(smem + 20480);     // ctx: [128 (h,b)][40]
  u16* sWloP = (u16*)(smem + 30720);
  u16* sWo   = (u16*)(smem);             // ho:  [256 r][40]
  u16* XBh   = (u16*)(smem + 20480);     // [16 b][264 c]
  u16* XBl   = (u16*)(smem + 28928);
  u16* XAh   = (u16*)(smem + 40960);
  u16* XAl   = (u16*)(smem + 49408);

  if (tid < 128)
    sli[tid] = 1.f / lbuf[(size_t)((b0 + (tid & 15)) * 64) + f * 8 + (tid >> 4)];
  __syncthreads();

  // ---- ctx: per-ks panels of Wv (all h) and normalized w (all h, hi/lo) ----
  f32x4 cacc0 = (f32x4){0.f, 0.f, 0.f, 0.f};
  f32x4 cacc1 = (f32x4){0.f, 0.f, 0.f, 0.f};
  for (int ks = 0; ks < 8; ++ks) {
    #pragma unroll
    for (int p = 0; p < 4; ++p) {        // Wv panel: 256 rows (h*32+d) x 32 c
      int idx = tid + 512 * p;
      int r = idx >> 3, cq = (idx & 7) * 4;
      float4 v = *(const float4*)&ipw[((size_t)(f * 768 + 512) + r) * 256 + ks * 32 + cq];
      *(ushort4*)&sWvP[r * 40 + cq] = make_ushort4(f2b(v.x), f2b(v.y), f2b(v.z), f2b(v.w));
    }
    #pragma unroll
    for (int p = 0; p < 2; ++p) {        // w panel: 128 rows (h*16+b) x 32 j, x 1/l, hi/lo
      int idx = tid + 512 * p;
      int rr = idx >> 3, cq = (idx & 7) * 4;
      int h = rr >> 4, b = rr & 15;
      float li = sli[rr];
      float4 v = *(const float4*)&wbuf[((size_t)((b0 + b) * 64) + f * 8 + h) * 256 + ks * 32 + cq];
      v.x *= li; v.y *= li; v.z *= li; v.w *= li;
      u16 hx = f2b(v.x), hy = f2b(v.y), hz = f2b(v.z), hw2 = f2b(v.w);
      *(ushort4*)&sWhiP[rr * 40 + cq] = make_ushort4(hx, hy, hz, hw2);
      *(ushort4*)&sWloP[rr * 40 + cq] = make_ushort4(
          f2b(v.x - b2f(hx)), f2b(v.y - b2f(hy)), f2b(v.z - b2f(hz)), f2b(v.w - b2f(hw2)));
    }
    __syncthreads();
    bf16x8 bh = *(bf16x8*)&sWhiP[(w * 16 + col) * 40 + khi * 8];
    bf16x8 bl = *(bf16x8*)&sWloP[(w * 16 + col) * 40 + khi * 8];
    bf16x8 a0 = *(bf16x8*)&sWvP[(w * 32 + col) * 40 + khi * 8];
    bf16x8 a1 = *(bf16x8*)&sWvP[(w * 32 + 16 + col) * 40 + khi * 8];
    cacc0 = MFMA(a0, bh, cacc0); cacc0 = MFMA(a0, bl, cacc0);
    cacc1 = MFMA(a1, bh, cacc1); cacc1 = MFMA(a1, bl, cacc1);
    __syncthreads();
  }
  // ctx + bv -> XA hi/lo. lane owns (d = mt*16+khi*4+r, b = col) for h = w.
  #pragma unroll
  for (int mt = 0; mt < 2; ++mt) {
    f32x4 cv = mt ? cacc1 : cacc0;
    #pragma unroll
    for (int r = 0; r < 4; ++r) {
      int d = mt * 16 + khi * 4 + r;
      float vv = cv[r] + ipb[f * 768 + 512 + w * 32 + d];
      u16 hi = f2b(vv);
      XAh[col * 264 + w * 32 + d] = hi;
      XAl[col * 264 + w * 32 + d] = f2b(vv - b2f(hi));
    }
  }

  // ---- ho0: D[b][x] = ctx . Wo^T + bo ; waves own x-tiles (w*2+q)*16 ----
  f32x4 hr0, hr1;
  {
    float bo0 = opb[f * 256 + (w * 2 + 0) * 16 + col];
    float bo1 = opb[f * 256 + (w * 2 + 1) * 16 + col];
    hr0 = (f32x4){bo0, bo0, bo0, bo0};
    hr1 = (f32x4){bo1, bo1, bo1, bo1};
  }
  for (int ks = 0; ks < 8; ++ks) {
    #pragma unroll
    for (int p = 0; p < 4; ++p) {        // Wo panel: 256 r x 32 c
      int idx = tid + 512 * p;
      int r = idx >> 3, cq = (idx & 7) * 4;
      float4 v = *(const float4*)&opw[((size_t)(f * 256) + r) * 256 + ks * 32 + cq];
      *(ushort4*)&sWo[r * 40 + cq] = make_ushort4(f2b(v.x), f2b(v.y), f2b(v.z), f2b(v.w));
    }
    __syncthreads();
    bf16x8 ah  = *(bf16x8*)&XAh[col * 264 + ks * 32 + khi * 8];
    bf16x8 al  = *(bf16x8*)&XAl[col * 264 + ks * 32 + khi * 8];
    bf16x8 bw0 = *(bf16x8*)&sWo[((w * 2 + 0) * 16 + col) * 40 + khi * 8];
    bf16x8 bw1 = *(bf16x8*)&sWo[((w * 2 + 1) * 16 + col) * 40 + khi * 8];
    hr0 = MFMA(ah, bw0, hr0); hr0 = MFMA(al, bw0, hr0);
    hr1 = MFMA(ah, bw1, hr1); hr1 = MFMA(al, bw1, hr1);
    __syncthreads();
  }

  // spill ho hi/lo to LDS buffer (Oh/Ol); residual fp32 stays in hr0/hr1
  auto spill = [&](u16* Oh, u16* Ol) {
    #pragma unroll
    for (int q = 0; q < 2; ++q) {
      f32x4 hv = q ? hr1 : hr0;
      int x = (w * 2 + q) * 16 + col;
      #pragma unroll
      for (int r = 0; r < 4; ++r) {
        u16 hi = f2b(hv[r]);
        Oh[(khi * 4 + r) * 264 + x] = hi;
        Ol[(khi * 4 + r) * 264 + x] = f2b(hv[r] - b2f(hi));
      }
    }
  };
  // one meta step: hr += (ho_s) @ meta[s], A = ho_s hi/lo, B = metaT (exact bf16)
  auto meta_mm = [&](const u16* Ah_, const u16* Al_, int s) {
    f32x4 n0 = hr0, n1 = hr1;
    #pragma unroll
    for (int ks = 0; ks < 8; ++ks) {
      bf16x8 ah = *(const bf16x8*)&Ah_[col * 264 + ks * 32 + khi * 8];
      bf16x8 al = *(const bf16x8*)&Al_[col * 264 + ks * 32 + khi * 8];
      const u16* mrow = &metaT[((size_t)(s * 256) + (w * 2) * 16 + col) * 256 + ks * 32 + khi * 8];
      bf16x8 m0 = *(const bf16x8*)mrow;
      bf16x8 m1 = *(const bf16x8*)(mrow + 16 * 256);
      n0 = MFMA(ah, m0, n0); n0 = MFMA(al, m0, n0);
      n1 = MFMA(ah, m1, n1); n1 = MFMA(al, m1, n1);
    }
    hr0 = n0; hr1 = n1;
  };

  spill(XBh, XBl);            // ho0
  __syncthreads();
  meta_mm(XBh, XBl, 0);
  spill(XAh, XAl);
  __syncthreads();
  meta_mm(XAh, XAl, 1);
  spill(XBh, XBl);
  __syncthreads();
  meta_mm(XBh, XBl, 2);

  // fused k6: out[b][x] += strat[b][f] * ho  (out pre-zeroed; 8 adds/address)
  #pragma unroll
  for (int q = 0; q < 2; ++q) {
    f32x4 hv = q ? hr1 : hr0;
    int x = (w * 2 + q) * 16 + col;
    #pragma unroll
    for (int r = 0; r < 4; ++r) {
      int b = khi * 4 + r;
      float sv = strat[(b0 + b) * F_ + f];
      atomicAdd(&out[(size_t)(b0 + b) * H_ + x], sv * hv[r]);
    }
  }
}

extern "C" void kernel_launch(void* const* d_in, const int* in_sizes, int n_in,
                              void* d_out, int out_size, void* d_ws, size_t ws_size,
                              hipStream_t stream) {
  const float* query = (const float*)d_in[0];
  const float* docs  = (const float*)d_in[1];
  const float* cw    = (const float*)d_in[2];
  // d_in[3] context_history: unused by the reference
  const float* ipw   = (const float*)d_in[4];
  const float* ipb   = (const float*)d_in[5];
  const float* opw   = (const float*)d_in[6];
  const float* opb   = (const float*)d_in[7];
  const float* stw   = (const float*)d_in[8];
  const float* stb   = (const float*)d_in[9];
  const float* meta  = (const float*)d_in[10];
  float* out = (float*)d_out;

  char* base = (char*)d_ws;
  u16*   u     = (u16*)(base + UB_U);
  float* wbuf  = (float*)(base + UB_W);
  float* lbuf  = (float*)(base + UB_L);
  float* strat = (float*)(base + UB_STRAT);
  u16*   metaT = (u16*)(base + UB_MT);

  hipMemsetAsync(out, 0, (size_t)B_ * H_ * sizeof(float), stream);
  hipMemsetAsync(base + UB_W, 0,
                 (size_t)(B_ * FH_ * H_ * sizeof(float) + B_ * FH_ * sizeof(float)),
                 stream);
  k1_fused<<<dim3(40), 512, 0, stream>>>(query, ipw, ipb, stw, stb, meta, u, metaT, strat);
  k4_one<<<dim3(NCH_, B_), 512, 0, stream>>>(docs, cw, u, wbuf, lbuf);
  k5_mfma<<<dim3(16), 512, 0, stream>>>(ipw, ipb, opw, opb, metaT, wbuf, lbuf, strat, out);
}

// Round 6
// 192.555 us; speedup vs baseline: 1.5333x; 1.0158x over previous
//
#include <hip/hip_runtime.h>
#include <hip/hip_bf16.h>

// MetaAdaptiveFusion: B=32, N=2048, H=256, F=8, NH=8, dh=32, 3 meta steps.
// Inputs: fp32 buffers holding bf16-quantized values -> bf16 casts of INPUTS are
// LOSSLESS. Computed activations (qh, w, ctx, ho, e*cw) are hi/lo-split
// compensated bf16; residual carries stay fp32. Output fp32.
//
// R13: k5_mfma (40.9us; MfmaUtil 0.24%, occupancy 0.97% -> 16 blocks, 16
// barrier-separated LDS staging rounds, pure exposed-latency) rewritten with
// ZERO weight staging: Wv/Wo fragments are wave-private, so they load directly
// global->register (fully unrolled, all loads concurrent; ILP replaces TLP).
// 1/l scaling is per-lane. LDS keeps only cross-wave XA/XB activation buffers
// (34KB); barriers 19 -> 5. Math order identical to R12 -> absmax unchanged.
// Pipeline: memset(out); memset(wbuf+lbuf); k1_fused; k4_one; k5_mfma.
// Fragment layouts per verified gfx950 conventions (A: m=lane&15,
// k=(lane>>4)*8+j ; B: n=lane&15 same k ; D: col=lane&15, row=(lane>>4)*4+reg).

#define B_ 32
#define N_ 2048
#define H_ 256
#define F_ 8
#define FH_ 64
#define NCH_ 8   // 8 n-split blocks of 256 docs

typedef unsigned short u16;
typedef __attribute__((ext_vector_type(8))) short bf16x8;   // 8 bf16 (4 VGPRs)
typedef __attribute__((ext_vector_type(4))) float f32x4;
#define MFMA(a, b, c) __builtin_amdgcn_mfma_f32_16x16x32_bf16((a), (b), (c), 0, 0, 0)

__device__ __forceinline__ u16 f2b(float x) {   // fp32 -> bf16 bits, RNE
  unsigned u = __builtin_bit_cast(unsigned, x);
  return (u16)((u + 0x7fffu + ((u >> 16) & 1u)) >> 16);
}
__device__ __forceinline__ float b2f(u16 h) {
  unsigned u = ((unsigned)h) << 16;
  return __builtin_bit_cast(float, u);
}
__device__ __forceinline__ bf16x8 ld8b(const float* p) {  // 8 fp32 -> bf16x8
  float4 v0 = *(const float4*)p, v1 = *(const float4*)(p + 4);
  bf16x8 a;
  a[0] = f2b(v0.x); a[1] = f2b(v0.y); a[2] = f2b(v0.z); a[3] = f2b(v0.w);
  a[4] = f2b(v1.x); a[5] = f2b(v1.y); a[6] = f2b(v1.z); a[7] = f2b(v1.w);
  return a;
}

// ---- ws byte layout (<= 3,548,160 B; 3,687,424 proven safe in R6) ----
static constexpr size_t UB_U     = 0;          // u16 [B][FH][H]    1,048,576
static constexpr size_t UB_W     = 1048576;    // f32 [B][FH][H]    2,097,152
static constexpr size_t UB_L     = 3145728;    // f32 [B][FH]           8,192
static constexpr size_t UB_STRAT = 3153920;    // f32 [B][F]            1,024
static constexpr size_t UB_MT    = 3154944;    // u16 [3][256][256]   393,216

// =============== K1_FUSED: MFMA qh -> u, strategy  |  metaT transpose ============
// grid 40, 512 thr. Blocks 0..15: (f 8) x (h-half 2) qh/u/strategy.
// Blocks 16..39: (s 3) x (xg 8) meta -> bf16 metaT[s][x][r] (meta bf16-exact).
__global__ __launch_bounds__(512) void k1_fused(
    const float* __restrict__ query, const float* __restrict__ ipw,
    const float* __restrict__ ipb, const float* __restrict__ stw,
    const float* __restrict__ stb, const float* __restrict__ meta,
    u16* __restrict__ u, u16* __restrict__ metaT, float* __restrict__ strat)
{
  const int tid = threadIdx.x, L = tid & 63, w = tid >> 6;
  const int khi = L >> 4, col = L & 15;

  if (blockIdx.x >= 16) {   // ---- kt part: metaT ----
    const int bid2 = blockIdx.x - 16;
    const int s = bid2 >> 3, x0 = (bid2 & 7) * 32;
    __shared__ u16 sT[32 * 264];               // [32 x][264 r]
    #pragma unroll
    for (int p = 0; p < 4; ++p) {              // load 256 r x 32 x, coalesced
      int idx = tid + 512 * p;
      int r = idx >> 3, xq = (idx & 7) * 4;
      float4 v = *(const float4*)&meta[((size_t)(s * 256) + r) * 256 + x0 + xq];
      sT[(xq + 0) * 264 + r] = f2b(v.x);
      sT[(xq + 1) * 264 + r] = f2b(v.y);
      sT[(xq + 2) * 264 + r] = f2b(v.z);
      sT[(xq + 3) * 264 + r] = f2b(v.w);
    }
    __syncthreads();
    #pragma unroll
    for (int p = 0; p < 2; ++p) {              // store rows of metaT, 16B chunks
      int idx = tid + 512 * p;
      int x = idx >> 5, rq = (idx & 31) * 8;
      bf16x8 v = *(bf16x8*)&sT[x * 264 + rq];
      *(bf16x8*)&metaT[((size_t)(s * 256) + x0 + x) * 256 + rq] = v;
    }
    return;
  }

  // ---- k1 part ----
  const int f = blockIdx.x >> 1, hf = blockIdx.x & 1;
  __shared__ u16 sW[256 * 40];     // phase1: Wq panel [128][40]; phase2: WkT [256 j][40 d-swz]
  __shared__ u16 qhh[32 * 136];    // qh hi [32 b][136 r-local]
  __shared__ u16 qhl[32 * 136];    // qh lo
  __shared__ float slog[256];      // strategy logits [32 b][8 i]

  // query B-frags (bf16-exact), loop-invariant: qf[bt][ks]
  bf16x8 qf[2][8];
  #pragma unroll
  for (int bt = 0; bt < 2; ++bt)
    #pragma unroll
    for (int ks = 0; ks < 8; ++ks)
      qf[bt][ks] = ld8b(&query[(size_t)(bt * 16 + col) * H_ + ks * 32 + khi * 8]);

  // strategy logits via MFMA (block 0, wave 0). A = stw rows (col<8), B = qf.
  if (f == 0 && hf == 0 && w == 0) {
    f32x4 sacc[2] = {(f32x4){0.f,0.f,0.f,0.f}, (f32x4){0.f,0.f,0.f,0.f}};
    #pragma unroll
    for (int ks = 0; ks < 8; ++ks) {
      bf16x8 a = (bf16x8){0,0,0,0,0,0,0,0};
      if (col < 8) a = ld8b(&stw[(size_t)col * H_ + ks * 32 + khi * 8]);
      sacc[0] = MFMA(a, qf[0][ks], sacc[0]);
      sacc[1] = MFMA(a, qf[1][ks], sacc[1]);
    }
    if (khi < 2) {   // D row = i = khi*4+r (<8), col -> b
      #pragma unroll
      for (int bt = 0; bt < 2; ++bt)
        #pragma unroll
        for (int r = 0; r < 4; ++r) {
          int i = khi * 4 + r;
          slog[(bt * 16 + col) * 8 + i] = sacc[bt][r] + stb[i];
        }
    }
  }

  // ---- phase 1: qh GEMM ----
  f32x4 qacc[2] = {(f32x4){0.f,0.f,0.f,0.f}, (f32x4){0.f,0.f,0.f,0.f}};
  for (int ks = 0; ks < 8; ++ks) {
    #pragma unroll
    for (int p = 0; p < 2; ++p) {    // Wq panel: 128 r x 32 k, coalesced
      int gid = tid + 512 * p;
      int r = gid >> 3, kq = (gid & 7) * 4;
      float4 v = *(const float4*)&ipw[((size_t)(f * 768) + hf * 128 + r) * H_ + ks * 32 + kq];
      *(ushort4*)&sW[r * 40 + kq] = make_ushort4(f2b(v.x), f2b(v.y), f2b(v.z), f2b(v.w));
    }
    __syncthreads();
    bf16x8 a = *(const bf16x8*)&sW[(w * 16 + col) * 40 + khi * 8];
    qacc[0] = MFMA(a, qf[0][ks], qacc[0]);
    qacc[1] = MFMA(a, qf[1][ks], qacc[1]);
    __syncthreads();
  }
  // epilogue: + bq, hi/lo split -> qhh/qhl. lane: r = w*16+khi*4+reg, b = bt*16+col
  {
    int r0 = w * 16 + khi * 4;
    float4 bq = *(const float4*)&ipb[f * 768 + hf * 128 + r0];
    #pragma unroll
    for (int bt = 0; bt < 2; ++bt) {
      int b = bt * 16 + col;
      float v0 = qacc[bt][0] + bq.x, v1 = qacc[bt][1] + bq.y;
      float v2 = qacc[bt][2] + bq.z, v3 = qacc[bt][3] + bq.w;
      ushort4 hs = make_ushort4(f2b(v0), f2b(v1), f2b(v2), f2b(v3));
      ushort4 ls = make_ushort4(f2b(v0 - b2f(hs.x)), f2b(v1 - b2f(hs.y)),
                                f2b(v2 - b2f(hs.z)), f2b(v3 - b2f(hs.w)));
      *(ushort4*)&qhh[b * 136 + r0] = hs;
      *(ushort4*)&qhl[b * 136 + r0] = ls;
    }
  }
  __syncthreads();

  // strategy softmax (block 0; slog written by wave 0, all waves synced since)
  if (f == 0 && hf == 0 && tid < 32) {
    float mx = slog[tid * 8];
    #pragma unroll
    for (int i = 1; i < F_; ++i) mx = fmaxf(mx, slog[tid * 8 + i]);
    float s = 0.f, e[F_];
    #pragma unroll
    for (int i = 0; i < F_; ++i) { e[i] = __expf(slog[tid * 8 + i] - mx); s += e[i]; }
    #pragma unroll
    for (int i = 0; i < F_; ++i) strat[tid * F_ + i] = e[i] / s;
  }

  // ---- phase 2: u per head ----
  const float scale = 0.17677669529663687f;
  for (int hh = 0; hh < 4; ++hh) {
    #pragma unroll
    for (int p = 0; p < 4; ++p) {    // WkT stage: read rows coalesced, write transposed+swizzled
      int gid = tid + 512 * p;
      int d = gid >> 6, jq = (gid & 63) * 4;
      float4 v = *(const float4*)&ipw[((size_t)(f * 768 + 256) + (hf * 4 + hh) * 32 + d) * H_ + jq];
      float vv[4] = {v.x, v.y, v.z, v.w};
      #pragma unroll
      for (int e = 0; e < 4; ++e) {
        int j = jq + e;
        sW[j * 40 + (d ^ (((j >> 4) & 3) << 3))] = f2b(vv[e]);
      }
    }
    __syncthreads();
    #pragma unroll
    for (int q = 0; q < 2; ++q) {
      int jt = w * 2 + q;
      bf16x8 a = *(const bf16x8*)&sW[(jt * 16 + col) * 40 + ((khi ^ (jt & 3)) * 8)];
      #pragma unroll
      for (int bt = 0; bt < 2; ++bt) {
        int b = bt * 16 + col;
        bf16x8 bh = *(const bf16x8*)&qhh[b * 136 + hh * 32 + khi * 8];
        bf16x8 bl = *(const bf16x8*)&qhl[b * 136 + hh * 32 + khi * 8];
        f32x4 acc = (f32x4){0.f, 0.f, 0.f, 0.f};
        acc = MFMA(a, bh, acc);
        acc = MFMA(a, bl, acc);
        int j0 = jt * 16 + khi * 4;
        ushort4 us = make_ushort4(f2b(acc[0] * scale), f2b(acc[1] * scale),
                                  f2b(acc[2] * scale), f2b(acc[3] * scale));
        *(ushort4*)&u[((size_t)(b * 64) + f * 8 + hf * 4 + hh) * H_ + j0] = us;
      }
    }
    __syncthreads();
  }
}

// =============== K4_ONE: single docs pass, shift-free exp, W + l =================
// grid (8 ns, 32 b), 512 thr (8 waves). Block: n-range ns*256..+256, all 64 fh,
// all 256 j. W_unnorm in registers (acc2[4][2] f32x4/thread), 4 chunks of 64 n.
// e = exp((u.docs)*cw) (|score|<~0.4 -> no shift needed); W-weight = e*cw hi/lo;
// l[b][fh] += sum_n e via register accum + 16-lane shuffle + global atomics.
__global__ __launch_bounds__(512) void k4_one(
    const float* __restrict__ docs, const float* __restrict__ cw,
    const u16* __restrict__ u, float* __restrict__ wbuf, float* __restrict__ lbuf)
{
  const int ns = blockIdx.x, b = blockIdx.y;
  const int n0 = ns * 256;
  const int tid = threadIdx.x, L = tid & 63, w = tid >> 6;
  const int khi = L >> 4, col = L & 15;
  const int ft = w & 3, nt0 = (w >> 2) * 2;

  __shared__ u16 sdu[64 * 264];     // docs chunk [64 n][264 j] bf16, col-swizzled
  __shared__ u16 phu[64 * 72];      // (e*cw)_hi [64 fh][72 n]
  __shared__ u16 plou[64 * 72];     // (e*cw)_lo

  // loop-invariant u A-fragments for this wave's fh-tile ft
  bf16x8 uf[8];
  #pragma unroll
  for (int ks = 0; ks < 8; ++ks)
    uf[ks] = *(const bf16x8*)&u[((size_t)(b * 64) + ft * 16 + col) * H_ + ks * 32 + khi * 8];

  // prefetch + stage chunk 0 (swizzled store)
  float4 dv[8];
  #pragma unroll
  for (int p = 0; p < 8; ++p) {
    int idx = tid + 512 * p;
    int n = idx >> 6, jq = (idx & 63) * 4;
    dv[p] = *(const float4*)&docs[((size_t)(b * N_) + n0 + n) * H_ + jq];
  }
  #pragma unroll
  for (int p = 0; p < 8; ++p) {
    int idx = tid + 512 * p;
    int n = idx >> 6, jq = (idx & 63) * 4;
    *(ushort4*)&sdu[n * 264 + (jq ^ (((n >> 3) & 3) << 4))] =
        make_ushort4(f2b(dv[p].x), f2b(dv[p].y), f2b(dv[p].z), f2b(dv[p].w));
  }
  __syncthreads();

  f32x4 acc2[4][2];
  #pragma unroll
  for (int mt = 0; mt < 4; ++mt)
    #pragma unroll
    for (int jt = 0; jt < 2; ++jt) acc2[mt][jt] = (f32x4){0.f, 0.f, 0.f, 0.f};
  float eacc[4] = {0.f, 0.f, 0.f, 0.f};

  for (int nc = 0; nc < 4; ++nc) {
    // issue next chunk's global loads (latency hides under MFMA phases)
    if (nc < 3) {
      #pragma unroll
      for (int p = 0; p < 8; ++p) {
        int idx = tid + 512 * p;
        int n = idx >> 6, jq = (idx & 63) * 4;
        dv[p] = *(const float4*)&docs[((size_t)(b * N_) + n0 + (nc + 1) * 64 + n) * H_ + jq];
      }
    }
    // scores: D[fh(ft)][n(nt0,nt0+1)] = u . docs^T, K=256
    f32x4 sc0 = (f32x4){0.f, 0.f, 0.f, 0.f}, sc1 = sc0;
    const int nr0 = nt0 * 16 + col, nr1 = (nt0 + 1) * 16 + col;
    const int sw0 = ((nr0 >> 3) & 3) << 4, sw1 = ((nr1 >> 3) & 3) << 4;
    #pragma unroll
    for (int ks = 0; ks < 8; ++ks) {
      bf16x8 b0 = *(const bf16x8*)&sdu[nr0 * 264 + ((ks * 32 + khi * 8) ^ sw0)];
      bf16x8 b1 = *(const bf16x8*)&sdu[nr1 * 264 + ((ks * 32 + khi * 8) ^ sw1)];
      sc0 = MFMA(uf[ks], b0, sc0);
      sc1 = MFMA(uf[ks], b1, sc1);
    }
    // epilogue: e = exp(s*cw); weight = e*cw hi/lo; l-accum. lane: (fh, n=nt*16+col)
    {
      int ng = n0 + nc * 64 + nt0 * 16 + col;
      float cv0 = cw[(size_t)b * N_ + ng];
      float cv1 = cw[(size_t)b * N_ + ng + 16];
      #pragma unroll
      for (int r = 0; r < 4; ++r) {
        int fh = ft * 16 + khi * 4 + r;
        float ex0 = __expf(sc0[r] * cv0);
        float ex1 = __expf(sc1[r] * cv1);
        eacc[r] += ex0 + ex1;
        float p0 = ex0 * cv0, p1 = ex1 * cv1;
        u16 h0 = f2b(p0), h1 = f2b(p1);
        phu [fh * 72 + nt0 * 16 + col]       = h0;
        plou[fh * 72 + nt0 * 16 + col]       = f2b(p0 - b2f(h0));
        phu [fh * 72 + (nt0 + 1) * 16 + col] = h1;
        plou[fh * 72 + (nt0 + 1) * 16 + col] = f2b(p1 - b2f(h1));
      }
    }
    __syncthreads();   // weights visible to all waves; sdu intact

    // W[fh][j] += sum_n weight[fh][n] * docs[n][j]; wave owns j = w*32+jt*16+col
    #pragma unroll
    for (int kk = 0; kk < 2; ++kk) {
      #pragma unroll
      for (int jt = 0; jt < 2; ++jt) {
        int j = w * 32 + jt * 16 + col;
        bf16x8 bb;
        #pragma unroll
        for (int jj = 0; jj < 8; ++jj)
          bb[jj] = (short)sdu[(kk * 32 + khi * 8 + jj) * 264 + (j ^ (khi << 4))];
        #pragma unroll
        for (int mt = 0; mt < 4; ++mt) {
          bf16x8 ah = *(const bf16x8*)&phu [(mt * 16 + col) * 72 + kk * 32 + khi * 8];
          bf16x8 al = *(const bf16x8*)&plou[(mt * 16 + col) * 72 + kk * 32 + khi * 8];
          acc2[mt][jt] = MFMA(ah, bb, acc2[mt][jt]);
          acc2[mt][jt] = MFMA(al, bb, acc2[mt][jt]);
        }
      }
    }
    __syncthreads();   // all reads of sdu/weights done

    if (nc < 3) {      // stage next chunk from regs
      #pragma unroll
      for (int p = 0; p < 8; ++p) {
        int idx = tid + 512 * p;
        int n = idx >> 6, jq = (idx & 63) * 4;
        *(ushort4*)&sdu[n * 264 + (jq ^ (((n >> 3) & 3) << 4))] =
            make_ushort4(f2b(dv[p].x), f2b(dv[p].y), f2b(dv[p].z), f2b(dv[p].w));
      }
      __syncthreads();
    }
  }
  // merge partial W (one atomic per element; 8 adds per address across ns)
  #pragma unroll
  for (int mt = 0; mt < 4; ++mt)
    #pragma unroll
    for (int jt = 0; jt < 2; ++jt)
      #pragma unroll
      for (int r = 0; r < 4; ++r) {
        int fh = mt * 16 + khi * 4 + r;
        int j = w * 32 + jt * 16 + col;
        atomicAdd(&wbuf[((size_t)(b * 64) + fh) * H_ + j], acc2[mt][jt][r]);
      }
  // l partials: reduce over col (16 lanes), one atomic per (khi,r) lane group
  #pragma unroll
  for (int r = 0; r < 4; ++r) {
    float e = eacc[r];
    e += __shfl_xor(e, 1, 64);
    e += __shfl_xor(e, 2, 64);
    e += __shfl_xor(e, 4, 64);
    e += __shfl_xor(e, 8, 64);
    if (col == 0)
      atomicAdd(&lbuf[(size_t)(b * 64) + ft * 16 + khi * 4 + r], e);
  }
}

// =============== K5: MFMA chain ctx -> ho0 -> 3 meta steps -> out ================
// grid 16 = (f 8) x (b-tile 2 of 16 b), 512 threads (8 waves).
// Zero weight staging: Wv/Wo fragments are wave-private -> direct global->reg
// loads, fully unrolled (all concurrent; no barriers in the K loops). LDS holds
// only the cross-wave XA/XB activation buffers. 1/l scaling per-lane.
// Final epilogue: out[b][x] += strat[b][f] * ho (k6 fused; out pre-zeroed).
__global__ __launch_bounds__(512) void k5_mfma(
    const float* __restrict__ ipw, const float* __restrict__ ipb,
    const float* __restrict__ opw, const float* __restrict__ opb,
    const u16* __restrict__ metaT, const float* __restrict__ wbuf,
    const float* __restrict__ lbuf, const float* __restrict__ strat,
    float* __restrict__ out)
{
  const int f = blockIdx.x & 7, b0 = (blockIdx.x >> 3) * 16;
  const int tid = threadIdx.x, L = tid & 63, w = tid >> 6;   // w = wave 0..7
  const int khi = L >> 4, col = L & 15;

  __shared__ u16 XAh[16 * 264], XAl[16 * 264];   // [16 b][264 c] hi/lo
  __shared__ u16 XBh[16 * 264], XBl[16 * 264];

  // ---- ctx: wave w = head h. D[d(2x16 tiles)][b(16)] = Wv_h . (w/l)_h^T ----
  // A-frags: Wv rows w*32+mt*16+col, direct from global (bf16-exact).
  bf16x8 av[2][8];
  #pragma unroll
  for (int mt = 0; mt < 2; ++mt)
    #pragma unroll
    for (int ks = 0; ks < 8; ++ks)
      av[mt][ks] = ld8b(&ipw[((size_t)(f * 768 + 512) + w * 32 + mt * 16 + col) * H_
                             + ks * 32 + khi * 8]);
  // B-frags: lane-private wbuf row (b=b0+col, fh=f*8+w), scaled 1/l, hi/lo.
  const size_t wrow = ((size_t)((b0 + col) * 64) + f * 8 + w) * H_;
  const float li = 1.f / lbuf[(size_t)((b0 + col) * 64) + f * 8 + w];
  f32x4 cacc0 = (f32x4){0.f, 0.f, 0.f, 0.f};
  f32x4 cacc1 = (f32x4){0.f, 0.f, 0.f, 0.f};
  #pragma unroll
  for (int ks = 0; ks < 8; ++ks) {
    const float* p = &wbuf[wrow + ks * 32 + khi * 8];
    float4 v0 = *(const float4*)p, v1 = *(const float4*)(p + 4);
    float vv[8] = {v0.x, v0.y, v0.z, v0.w, v1.x, v1.y, v1.z, v1.w};
    bf16x8 bh, bl;
    #pragma unroll
    for (int e = 0; e < 8; ++e) {
      float x = vv[e] * li;
      u16 h = f2b(x);
      bh[e] = (short)h;
      bl[e] = (short)f2b(x - b2f(h));
    }
    cacc0 = MFMA(av[0][ks], bh, cacc0); cacc0 = MFMA(av[0][ks], bl, cacc0);
    cacc1 = MFMA(av[1][ks], bh, cacc1); cacc1 = MFMA(av[1][ks], bl, cacc1);
  }
  // ctx + bv -> XA hi/lo. lane owns (d = mt*16+khi*4+r, b = col) for h = w.
  #pragma unroll
  for (int mt = 0; mt < 2; ++mt) {
    f32x4 cv = mt ? cacc1 : cacc0;
    #pragma unroll
    for (int r = 0; r < 4; ++r) {
      int d = mt * 16 + khi * 4 + r;
      float vv = cv[r] + ipb[f * 768 + 512 + w * 32 + d];
      u16 hi = f2b(vv);
      XAh[col * 264 + w * 32 + d] = hi;
      XAl[col * 264 + w * 32 + d] = f2b(vv - b2f(hi));
    }
  }

  // prefetch Wo B-frags (wave-private rows (w*2+q)*16+col) before the barrier
  bf16x8 bw[2][8];
  #pragma unroll
  for (int q = 0; q < 2; ++q)
    #pragma unroll
    for (int ks = 0; ks < 8; ++ks)
      bw[q][ks] = ld8b(&opw[((size_t)(f * 256) + (w * 2 + q) * 16 + col) * H_
                            + ks * 32 + khi * 8]);
  __syncthreads();   // XA complete

  // ---- ho0: D[b][x] = ctx . Wo^T + bo ; waves own x-tiles (w*2+q)*16 ----
  f32x4 hr0, hr1;
  {
    float bo0 = opb[f * 256 + (w * 2 + 0) * 16 + col];
    float bo1 = opb[f * 256 + (w * 2 + 1) * 16 + col];
    hr0 = (f32x4){bo0, bo0, bo0, bo0};
    hr1 = (f32x4){bo1, bo1, bo1, bo1};
  }
  #pragma unroll
  for (int ks = 0; ks < 8; ++ks) {
    bf16x8 ah = *(const bf16x8*)&XAh[col * 264 + ks * 32 + khi * 8];
    bf16x8 al = *(const bf16x8*)&XAl[col * 264 + ks * 32 + khi * 8];
    hr0 = MFMA(ah, bw[0][ks], hr0); hr0 = MFMA(al, bw[0][ks], hr0);
    hr1 = MFMA(ah, bw[1][ks], hr1); hr1 = MFMA(al, bw[1][ks], hr1);
  }

  // spill ho hi/lo to LDS buffer (Oh/Ol); residual fp32 stays in hr0/hr1
  auto spill = [&](u16* Oh, u16* Ol) {
    #pragma unroll
    for (int q = 0; q < 2; ++q) {
      f32x4 hv = q ? hr1 : hr0;
      int x = (w * 2 + q) * 16 + col;
      #pragma unroll
      for (int r = 0; r < 4; ++r) {
        u16 hi = f2b(hv[r]);
        Oh[(khi * 4 + r) * 264 + x] = hi;
        Ol[(khi * 4 + r) * 264 + x] = f2b(hv[r] - b2f(hi));
      }
    }
  };
  // one meta step: hr += (ho_s) @ meta[s], A = ho_s hi/lo, B = metaT (exact bf16)
  auto meta_mm = [&](const u16* Ah_, const u16* Al_, int s) {
    f32x4 n0 = hr0, n1 = hr1;
    #pragma unroll
    for (int ks = 0; ks < 8; ++ks) {
      bf16x8 ah = *(const bf16x8*)&Ah_[col * 264 + ks * 32 + khi * 8];
      bf16x8 al = *(const bf16x8*)&Al_[col * 264 + ks * 32 + khi * 8];
      const u16* mrow = &metaT[((size_t)(s * 256) + (w * 2) * 16 + col) * 256 + ks * 32 + khi * 8];
      bf16x8 m0 = *(const bf16x8*)mrow;
      bf16x8 m1 = *(const bf16x8*)(mrow + 16 * 256);
      n0 = MFMA(ah, m0, n0); n0 = MFMA(al, m0, n0);
      n1 = MFMA(ah, m1, n1); n1 = MFMA(al, m1, n1);
    }
    hr0 = n0; hr1 = n1;
  };

  spill(XBh, XBl);            // ho0
  __syncthreads();
  meta_mm(XBh, XBl, 0);
  spill(XAh, XAl);
  __syncthreads();
  meta_mm(XAh, XAl, 1);
  spill(XBh, XBl);
  __syncthreads();
  meta_mm(XBh, XBl, 2);

  // fused k6: out[b][x] += strat[b][f] * ho  (out pre-zeroed; 8 adds/address)
  #pragma unroll
  for (int q = 0; q < 2; ++q) {
    f32x4 hv = q ? hr1 : hr0;
    int x = (w * 2 + q) * 16 + col;
    #pragma unroll
    for (int r = 0; r < 4; ++r) {
      int b = khi * 4 + r;
      float sv = strat[(b0 + b) * F_ + f];
      atomicAdd(&out[(size_t)(b0 + b) * H_ + x], sv * hv[r]);
    }
  }
}

extern "C" void kernel_launch(void* const* d_in, const int* in_sizes, int n_in,
                              void* d_out, int out_size, void* d_ws, size_t ws_size,
                              hipStream_t stream) {
  const float* query = (const float*)d_in[0];
  const float* docs  = (const float*)d_in[1];
  const float* cw    = (const float*)d_in[2];
  // d_in[3] context_history: unused by the reference
  const float* ipw   = (const float*)d_in[4];
  const float* ipb   = (const float*)d_in[5];
  const float* opw   = (const float*)d_in[6];
  const float* opb   = (const float*)d_in[7];
  const float* stw   = (const float*)d_in[8];
  const float* stb   = (const float*)d_in[9];
  const float* meta  = (const float*)d_in[10];
  float* out = (float*)d_out;

  char* base = (char*)d_ws;
  u16*   u     = (u16*)(base + UB_U);
  float* wbuf  = (float*)(base + UB_W);
  float* lbuf  = (float*)(base + UB_L);
  float* strat = (float*)(base + UB_STRAT);
  u16*   metaT = (u16*)(base + UB_MT);

  hipMemsetAsync(out, 0, (size_t)B_ * H_ * sizeof(float), stream);
  hipMemsetAsync(base + UB_W, 0,
                 (size_t)(B_ * FH_ * H_ * sizeof(float) + B_ * FH_ * sizeof(float)),
                 stream);
  k1_fused<<<dim3(40), 512, 0, stream>>>(query, ipw, ipb, stw, stb, meta, u, metaT, strat);
  k4_one<<<dim3(NCH_, B_), 512, 0, stream>>>(docs, cw, u, wbuf, lbuf);
  k5_mfma<<<dim3(16), 512, 0, stream>>>(ipw, ipb, opw, opb, metaT, wbuf, lbuf, strat, out);
}